// Round 15
// baseline (1121.864 us; speedup 1.0000x reference)
//
#include <hip/hip_runtime.h>

#define NNODES 50000
#define NEDGES 800000
#define NGRAPH 500
#define CH 100
#define CIN0 33
#define BN_EPS 1e-5f
#define NSHARD 8
#define SHSTRIDE 1024   // floats per shard: [4 layers][sum128|sq128]

#define SCAN_TPB 256
#define SCAN_IPT 4
#define SCAN_TILE (SCAN_TPB * SCAN_IPT)
#define SCAN_BLOCKS ((NNODES + SCAN_TILE - 1) / SCAN_TILE)

// pack two fp32 into (bf16(x) | bf16(y)<<16), round-to-nearest-even
__device__ inline unsigned pack_bf16(float x, float y) {
    unsigned xb = __float_as_uint(x);
    unsigned yb = __float_as_uint(y);
    xb += 0x7FFF + ((xb >> 16) & 1);
    yb += 0x7FFF + ((yb >> 16) & 1);
    return (xb >> 16) | (yb & 0xFFFF0000u);
}
__device__ inline float unp_lo(unsigned v) { return __uint_as_float(v << 16); }
__device__ inline float unp_hi(unsigned v) { return __uint_as_float(v & 0xFFFF0000u); }

// ---------------- init: zero histogram counters + BN stat shards + pool accumulator ----------------
__global__ void k_init(int* __restrict__ cnt, float* __restrict__ stats,
                       float* __restrict__ gbuf) {
    int i = blockIdx.x * blockDim.x + threadIdx.x;
    if (i < NNODES) cnt[i] = 0;
    if (i < NGRAPH * CH) gbuf[i] = 0.f;   // NGRAPH*CH == NNODES
    if (i < NSHARD * SHSTRIDE) stats[i] = 0.f;
}

// ---------------- in-degree histogram over dst ----------------
__global__ void k_hist(const int* __restrict__ dst, int* __restrict__ cnt) {
    int e = blockIdx.x * blockDim.x + threadIdx.x;
    if (e < NEDGES) atomicAdd(&cnt[dst[e]], 1);
}

// ---------------- pack x (50000 x 33 fp32) into bf16 rows of 17 uints ----------------
__global__ void k_packx(const float* __restrict__ x, unsigned* __restrict__ xb) {
    int i = blockIdx.x * blockDim.x + threadIdx.x;
    if (i >= NNODES * 17) return;
    int r = i / 17, s = i % 17;
    float a = x[r * CIN0 + 2 * s];
    float b = (2 * s + 1 < CIN0) ? x[r * CIN0 + 2 * s + 1] : 0.f;
    xb[i] = pack_bf16(a, b);
}

// ---------------- exclusive scan of cnt -> rowptr; also dinv = rsqrt(cnt+1) ----------------
__global__ void k_scan1(const int* __restrict__ cnt, int* __restrict__ rowptr,
                        int* __restrict__ blkSums, float* __restrict__ dinv) {
    __shared__ int ts[SCAN_TPB];
    int tid = threadIdx.x;
    int base = blockIdx.x * SCAN_TILE + tid * SCAN_IPT;
    int v[SCAN_IPT];
    int s = 0;
    #pragma unroll
    for (int j = 0; j < SCAN_IPT; ++j) {
        int i = base + j;
        v[j] = (i < NNODES) ? cnt[i] : 0;
        if (i < NNODES) dinv[i] = rsqrtf((float)(v[j] + 1));
        s += v[j];
    }
    ts[tid] = s;
    __syncthreads();
    for (int off = 1; off < SCAN_TPB; off <<= 1) {
        int add = (tid >= off) ? ts[tid - off] : 0;
        __syncthreads();
        ts[tid] += add;
        __syncthreads();
    }
    int run = ts[tid] - s;  // exclusive prefix within block
    #pragma unroll
    for (int j = 0; j < SCAN_IPT; ++j) {
        int i = base + j;
        if (i < NNODES) rowptr[i] = run;
        run += v[j];
    }
    if (tid == SCAN_TPB - 1) blkSums[blockIdx.x] = ts[tid];
}

__global__ void k_scan2(const int* __restrict__ blkSums, int* __restrict__ blkOff) {
    if (threadIdx.x == 0) {
        int run = 0;
        for (int i = 0; i < SCAN_BLOCKS; ++i) { blkOff[i] = run; run += blkSums[i]; }
    }
}

__global__ void k_scan3(int* __restrict__ rowptr, int* __restrict__ cursor,
                        const int* __restrict__ blkOff) {
    int off = blkOff[blockIdx.x];
    int base = blockIdx.x * SCAN_TILE + threadIdx.x * SCAN_IPT;
    #pragma unroll
    for (int j = 0; j < SCAN_IPT; ++j) {
        int i = base + j;
        if (i < NNODES) {
            int vv = rowptr[i] + off;
            rowptr[i] = vv;
            cursor[i] = vv;
        }
    }
    if (blockIdx.x == 0 && threadIdx.x == 0) rowptr[NNODES] = NEDGES;
}

// ---------------- scatter edges into CSR (by dst); pack (src, dinv[src]) ----------------
__global__ void k_scatter(const int* __restrict__ src, const int* __restrict__ dst,
                          const float* __restrict__ dinv, int* __restrict__ cursor,
                          int2* __restrict__ ew) {
    int e = blockIdx.x * blockDim.x + threadIdx.x;
    if (e < NEDGES) {
        int d = dst[e], s = src[e];
        int pos = atomicAdd(&cursor[d], 1);
        ew[pos] = make_int2(s, __float_as_int(dinv[s]));
    }
}

// ---------------- aggregate over bf16-packed rows, fused BN(+ReLU); fp32 output ----------------
// Input rows: CPACK uints (bf16 pairs). Lane l < CPACK owns channels (2l, 2l+1).
// a[i] = dinv[i]*( sum_e dinv[src]*f(h[src]) + dinv[i]*f(h[i]) ), f = BN affine+relu or id.
// Output fp32, row stride OS; pad pairs zero-filled.
template<int CPACK, int OS, bool BN>
__global__ __launch_bounds__(256) void k_aggregate_bf16(
    const unsigned* __restrict__ h, float* __restrict__ a, const int* __restrict__ rowptr,
    const int2* __restrict__ ew, const float* __restrict__ dinv,
    const float* __restrict__ gsum, const float* __restrict__ gsq,
    const float* __restrict__ gamma, const float* __restrict__ beta) {
    int node = (blockIdx.x * 256 + threadIdx.x) >> 6;
    int lane = threadIdx.x & 63;
    if (node >= NNODES) return;
    int p0 = rowptr[node], p1 = rowptr[node + 1];
    float di = dinv[node];
    constexpr float invN = 1.f / NNODES;
    bool act = lane < CPACK;

    float scx = 0.f, scy = 0.f, shx = 0.f, shy = 0.f;
    if (BN && act) {
        float sx = 0.f, sy = 0.f, qx = 0.f, qy = 0.f;
        #pragma unroll
        for (int sh = 0; sh < NSHARD; ++sh) {
            float2 s2 = ((const float2*)(gsum + sh * SHSTRIDE))[lane];
            float2 q2 = ((const float2*)(gsq + sh * SHSTRIDE))[lane];
            sx += s2.x; sy += s2.y; qx += q2.x; qy += q2.y;
        }
        float2 g2 = ((const float2*)gamma)[lane];
        float2 b2 = ((const float2*)beta)[lane];
        float mx = sx * invN, my = sy * invN;
        float vx = qx * invN - mx * mx, vy = qy * invN - my * my;
        scx = g2.x * rsqrtf(vx + BN_EPS); shx = b2.x - mx * scx;
        scy = g2.y * rsqrtf(vy + BN_EPS); shy = b2.y - my * scy;
    }
    unsigned hvp = 0;
    if (act) hvp = h[(size_t)node * CPACK + lane];

    float ax = 0.f, ay = 0.f;
    for (int base = p0; base < p1; base += 64) {
        int nn = p1 - base; if (nn > 64) nn = 64;
        int2 e = make_int2(0, 0);
        if (lane < nn) e = ew[base + lane];
        int myc = e.x; float myw = __int_as_float(e.y);
        int j = 0;
        for (; j + 16 <= nn; j += 16) {
            int s[16]; float w[16];
            #pragma unroll
            for (int t = 0; t < 16; ++t) { s[t] = __shfl(myc, j + t); w[t] = __shfl(myw, j + t); }
            if (act) {
                unsigned v[16];
                #pragma unroll
                for (int t = 0; t < 16; ++t) v[t] = h[(size_t)s[t] * CPACK + lane];
                #pragma unroll
                for (int t = 0; t < 16; ++t) {
                    float vx = unp_lo(v[t]), vy = unp_hi(v[t]);
                    if (BN) {
                        vx = fmaxf(vx * scx + shx, 0.f);
                        vy = fmaxf(vy * scy + shy, 0.f);
                    }
                    ax += w[t] * vx; ay += w[t] * vy;
                }
            }
        }
        for (; j + 4 <= nn; j += 4) {
            int s[4]; float w[4];
            #pragma unroll
            for (int t = 0; t < 4; ++t) { s[t] = __shfl(myc, j + t); w[t] = __shfl(myw, j + t); }
            if (act) {
                unsigned v[4];
                #pragma unroll
                for (int t = 0; t < 4; ++t) v[t] = h[(size_t)s[t] * CPACK + lane];
                #pragma unroll
                for (int t = 0; t < 4; ++t) {
                    float vx = unp_lo(v[t]), vy = unp_hi(v[t]);
                    if (BN) {
                        vx = fmaxf(vx * scx + shx, 0.f);
                        vy = fmaxf(vy * scy + shy, 0.f);
                    }
                    ax += w[t] * vx; ay += w[t] * vy;
                }
            }
        }
        for (; j < nn; ++j) {
            int s0 = __shfl(myc, j);
            float w0 = __shfl(myw, j);
            if (act) {
                unsigned v = h[(size_t)s0 * CPACK + lane];
                float vx = unp_lo(v), vy = unp_hi(v);
                if (BN) {
                    vx = fmaxf(vx * scx + shx, 0.f);
                    vy = fmaxf(vy * scy + shy, 0.f);
                }
                ax += w0 * vx; ay += w0 * vy;
            }
        }
    }
    if (lane < (OS + 1) / 2) {
        float2 o = make_float2(0.f, 0.f);
        if (act) {
            float hx = unp_lo(hvp), hy = unp_hi(hvp);
            if (BN) {
                hx = fmaxf(hx * scx + shx, 0.f);
                hy = fmaxf(hy * scy + shy, 0.f);
            }
            o.x = di * (ax + di * hx);
            o.y = di * (ay + di * hy);
        }
        ((float2*)(a + (size_t)node * OS))[lane] = o;
    }
}

// ---------------- CH-layer GEMM (512 thr, 4x4 micro-tile, K-split) -> bf16 Z + stats ----------------
// K staged in chunks of KC (52/48 for K=100): LDS 34.9 KB -> 4 blocks/CU (2x R14's
// occupancy). W chunk is a flat contiguous copy. acc persists across chunks.
template<int K, int KP, int KC>
__global__ __launch_bounds__(512) void k_gemm(
    const float* __restrict__ A, const float* __restrict__ W, const float* __restrict__ bias,
    unsigned* __restrict__ Zb, float* __restrict__ gsum, float* __restrict__ gsq) {
    __shared__ __align__(16) float wS[KC * CH];
    __shared__ __align__(16) float aS[64 * KC];
    __shared__ float sSum[CH], sSq[CH];
    int tid = threadIdx.x;
    for (int i = tid; i < CH; i += 512) { sSum[i] = 0.f; sSq[i] = 0.f; }
    int row0 = blockIdx.x * 64;
    int ct = tid % 25, rt = tid / 25;  // ct 0..24, rt 0..15 (for tid<400)
    int c0 = ct * 4, r0 = rt * 4;
    float acc[4][4] = {};

    for (int k0 = 0; k0 < K; k0 += KC) {
        int len = (K - k0 < KC) ? (K - k0) : KC;   // 52 then 48; both %4==0
        if (k0) __syncthreads();                   // prev chunk fully consumed
        // stage W chunk: rows k0..k0+len-1 are contiguous -> flat copy
        for (int i = tid; i < len * CH; i += 512) wS[i] = W[k0 * CH + i];
        // stage A chunk [64][len] at row stride KC
        for (int i = tid; i < 64 * len; i += 512) {
            int r = i / len, kk = i % len;
            int row = row0 + r;
            aS[r * KC + kk] = (row < NNODES) ? A[(size_t)row * KP + k0 + kk] : 0.f;
        }
        __syncthreads();
        if (tid < 400) {
            for (int k = 0; k < len; k += 4) {
                float4 w0 = *(const float4*)&wS[(k + 0) * CH + c0];
                float4 w1 = *(const float4*)&wS[(k + 1) * CH + c0];
                float4 w2 = *(const float4*)&wS[(k + 2) * CH + c0];
                float4 w3 = *(const float4*)&wS[(k + 3) * CH + c0];
                #pragma unroll
                for (int j = 0; j < 4; ++j) {
                    float4 av = *(const float4*)&aS[(r0 + j) * KC + k];
                    acc[j][0] += av.x * w0.x + av.y * w1.x + av.z * w2.x + av.w * w3.x;
                    acc[j][1] += av.x * w0.y + av.y * w1.y + av.z * w2.y + av.w * w3.y;
                    acc[j][2] += av.x * w0.z + av.y * w1.z + av.z * w2.z + av.w * w3.z;
                    acc[j][3] += av.x * w0.w + av.y * w1.w + av.z * w2.w + av.w * w3.w;
                }
            }
        }
    }

    if (tid < 400) {
        float4 bv = *(const float4*)&bias[c0];
        float cs0 = 0, cs1 = 0, cs2 = 0, cs3 = 0, cq0 = 0, cq1 = 0, cq2 = 0, cq3 = 0;
        #pragma unroll
        for (int j = 0; j < 4; ++j) {
            int r = row0 + r0 + j;
            if (r < NNODES) {
                float z0 = acc[j][0] + bv.x, z1 = acc[j][1] + bv.y;
                float z2 = acc[j][2] + bv.z, z3 = acc[j][3] + bv.w;
                *(uint2*)&Zb[(size_t)r * 50 + (c0 >> 1)] =
                    make_uint2(pack_bf16(z0, z1), pack_bf16(z2, z3));
                cs0 += z0; cs1 += z1; cs2 += z2; cs3 += z3;
                cq0 += z0 * z0; cq1 += z1 * z1; cq2 += z2 * z2; cq3 += z3 * z3;
            }
        }
        atomicAdd(&sSum[c0], cs0); atomicAdd(&sSum[c0 + 1], cs1);
        atomicAdd(&sSum[c0 + 2], cs2); atomicAdd(&sSum[c0 + 3], cs3);
        atomicAdd(&sSq[c0], cq0); atomicAdd(&sSq[c0 + 1], cq1);
        atomicAdd(&sSq[c0 + 2], cq2); atomicAdd(&sSq[c0 + 3], cq3);
    }
    __syncthreads();
    int sh = (blockIdx.x & (NSHARD - 1)) * SHSTRIDE;
    if (tid < CH) { atomicAdd(&gsum[sh + tid], sSum[tid]); atomicAdd(&gsq[sh + tid], sSq[tid]); }
}

// ---------------- layer-0 GEMM (256 thr, 64-row tile) -> bf16 Z + sharded stats ----------------
// Two sequential 4-row passes (unroll 1) keep only one 4x4 acc set live -> low VGPR.
__global__ __launch_bounds__(256) void k_gemm0(
    const float* __restrict__ A, const float* __restrict__ W, const float* __restrict__ bias,
    unsigned* __restrict__ Zb, float* __restrict__ gsum, float* __restrict__ gsq) {
    constexpr int K = CIN0, KP = 36;
    __shared__ __align__(16) float wS[KP * CH];
    __shared__ __align__(16) float aS[64 * KP];
    __shared__ float sSum[CH], sSq[CH];
    int tid = threadIdx.x;
    for (int i = tid; i < CH; i += 256) { sSum[i] = 0.f; sSq[i] = 0.f; }
    for (int i = tid; i < KP * CH; i += 256) wS[i] = (i < K * CH) ? W[i] : 0.f;
    int row0 = blockIdx.x * 64;
    {
        const float* Ab = A + (size_t)row0 * KP;
        int maxI = (NNODES - row0) * KP;
        for (int i = tid; i < 64 * KP; i += 256) aS[i] = (i < maxI) ? Ab[i] : 0.f;
    }
    __syncthreads();
    if (tid < 200) {
        int ct = tid % 25, rt = tid / 25;  // ct 0..24, rt 0..7
        int c0 = ct * 4;
        float4 bv = *(const float4*)&bias[c0];
        float cs0 = 0, cs1 = 0, cs2 = 0, cs3 = 0, cq0 = 0, cq1 = 0, cq2 = 0, cq3 = 0;
        #pragma unroll 1
        for (int half = 0; half < 2; ++half) {
            int r0 = rt * 8 + half * 4;
            float acc[4][4] = {};
            #pragma unroll
            for (int k = 0; k < KP; k += 4) {
                float4 w0 = *(const float4*)&wS[(k + 0) * CH + c0];
                float4 w1 = *(const float4*)&wS[(k + 1) * CH + c0];
                float4 w2 = *(const float4*)&wS[(k + 2) * CH + c0];
                float4 w3 = *(const float4*)&wS[(k + 3) * CH + c0];
                #pragma unroll
                for (int j = 0; j < 4; ++j) {
                    float4 av = *(const float4*)&aS[(r0 + j) * KP + k];
                    acc[j][0] += av.x * w0.x + av.y * w1.x + av.z * w2.x + av.w * w3.x;
                    acc[j][1] += av.x * w0.y + av.y * w1.y + av.z * w2.y + av.w * w3.y;
                    acc[j][2] += av.x * w0.z + av.y * w1.z + av.z * w2.z + av.w * w3.z;
                    acc[j][3] += av.x * w0.w + av.y * w1.w + av.z * w2.w + av.w * w3.w;
                }
            }
            #pragma unroll
            for (int j = 0; j < 4; ++j) {
                int r = row0 + r0 + j;
                if (r < NNODES) {
                    float z0 = acc[j][0] + bv.x, z1 = acc[j][1] + bv.y;
                    float z2 = acc[j][2] + bv.z, z3 = acc[j][3] + bv.w;
                    *(uint2*)&Zb[(size_t)r * 50 + (c0 >> 1)] =
                        make_uint2(pack_bf16(z0, z1), pack_bf16(z2, z3));
                    cs0 += z0; cs1 += z1; cs2 += z2; cs3 += z3;
                    cq0 += z0 * z0; cq1 += z1 * z1; cq2 += z2 * z2; cq3 += z3 * z3;
                }
            }
        }
        atomicAdd(&sSum[c0], cs0); atomicAdd(&sSum[c0 + 1], cs1);
        atomicAdd(&sSum[c0 + 2], cs2); atomicAdd(&sSum[c0 + 3], cs3);
        atomicAdd(&sSq[c0], cq0); atomicAdd(&sSq[c0 + 1], cq1);
        atomicAdd(&sSq[c0 + 2], cq2); atomicAdd(&sSq[c0 + 3], cq3);
    }
    __syncthreads();
    int sh = (blockIdx.x & (NSHARD - 1)) * SHSTRIDE;
    if (tid < CH) { atomicAdd(&gsum[sh + tid], sSum[tid]); atomicAdd(&gsq[sh + tid], sSq[tid]); }
}

// ---------------- global_add_pool of BN(z) from bf16 Z; 4 row-chunks per graph ----------------
__global__ void k_pool(const unsigned* __restrict__ Zl, const int* __restrict__ batch,
                       const float* __restrict__ gsum, const float* __restrict__ gsq,
                       const float* __restrict__ gamma, const float* __restrict__ beta,
                       float* __restrict__ g) {
    int gid = blockIdx.x;
    int part = blockIdx.y;
    int lo = 0, hi = NNODES;
    while (lo < hi) { int mid = (lo + hi) >> 1; if (batch[mid] < gid) lo = mid + 1; else hi = mid; }
    int start = lo;
    hi = NNODES;
    while (lo < hi) { int mid = (lo + hi) >> 1; if (batch[mid] < gid + 1) lo = mid + 1; else hi = mid; }
    int end = lo;
    int len = end - start;
    int cb = (len + 3) >> 2;
    int s = start + part * cb;
    int e = s + cb; if (e > end) e = end;
    if (s >= e) return;
    int t = threadIdx.x;
    if (t >= 50) return;
    float su = 0.f, sv = 0.f, qu = 0.f, qv = 0.f;
    #pragma unroll
    for (int sh = 0; sh < NSHARD; ++sh) {
        float2 s2 = ((const float2*)(gsum + sh * SHSTRIDE))[t];
        float2 q2 = ((const float2*)(gsq + sh * SHSTRIDE))[t];
        su += s2.x; sv += s2.y; qu += q2.x; qv += q2.y;
    }
    constexpr float invN = 1.f / NNODES;
    float2 g2 = ((const float2*)gamma)[t];
    float2 b2 = ((const float2*)beta)[t];
    float mx = su * invN, my = sv * invN;
    float vx = qu * invN - mx * mx, vy = qv * invN - my * my;
    float scx = g2.x * rsqrtf(vx + BN_EPS), shx = b2.x - mx * scx;
    float scy = g2.y * rsqrtf(vy + BN_EPS), shy = b2.y - my * scy;
    float sx = 0.f, sy = 0.f;
    for (int r = s; r < e; ++r) {
        unsigned v = Zl[(size_t)r * 50 + t];
        sx += unp_lo(v); sy += unp_hi(v);
    }
    float n = (float)(e - s);
    atomicAdd(&g[gid * CH + 2 * t], sx * scx + n * shx);
    atomicAdd(&g[gid * CH + 2 * t + 1], sy * scy + n * shy);
}

// ---------------- out = leakyrelu(g @ Wout + bout, 0.1) ----------------
__global__ __launch_bounds__(256) void k_out(const float* __restrict__ g,
                                             const float* __restrict__ Wout,
                                             const float* __restrict__ bout,
                                             float* __restrict__ out) {
    __shared__ float gS[CH];
    int gid = blockIdx.x, tid = threadIdx.x;
    if (tid < CH) gS[tid] = g[gid * CH + tid];
    __syncthreads();
    if (tid >= 200) return;
    float acc = bout[tid];
    for (int k = 0; k < CH; ++k) acc += gS[k] * Wout[k * 200 + tid];
    out[gid * 200 + tid] = acc > 0.f ? acc : 0.1f * acc;
}

extern "C" void kernel_launch(void* const* d_in, const int* in_sizes, int n_in,
                              void* d_out, int out_size, void* d_ws, size_t ws_size,
                              hipStream_t stream) {
    const float* x = (const float*)d_in[0];
    const int* ei = (const int*)d_in[1];
    const int* batch = (const int*)d_in[2];
    const float* W0 = (const float*)d_in[3];
    const float* Wrest = (const float*)d_in[4];
    const float* b = (const float*)d_in[5];
    const float* gamma = (const float*)d_in[6];
    const float* beta = (const float*)d_in[7];
    const float* Wout = (const float*)d_in[8];
    const float* bout = (const float*)d_in[9];
    float* out = (float*)d_out;
    const int* srcA = ei;
    const int* dstA = ei + NEDGES;

    char* wsb = (char*)d_ws;
    size_t off = 0;
    auto alloc = [&](size_t elems) -> void* {
        void* p = (void*)(wsb + off);
        off += ((elems + 7) & ~(size_t)7) * 4;
        return p;
    };
    int* cnt = (int*)alloc(NNODES);
    int* rowptr = (int*)alloc(NNODES + 1);
    int* cursor = (int*)alloc(NNODES);
    float* dinv = (float*)alloc(NNODES);
    int* scanBlk = (int*)alloc(64);
    int* scanOff = (int*)alloc(64);
    float* stats = (float*)alloc(NSHARD * SHSTRIDE);  // per shard: [l*128]=sum, [512+l*128]=sq
    int2* ew = (int2*)alloc(2 * (size_t)NEDGES);
    unsigned* xb = (unsigned*)alloc((size_t)NNODES * 17);
    float* Abuf = (float*)alloc((size_t)NNODES * CH);
    unsigned* Zb = (unsigned*)alloc((size_t)NNODES * 50);
    float* gbuf = (float*)alloc((size_t)NGRAPH * CH);
    (void)ws_size; (void)n_in; (void)in_sizes; (void)out_size;

    hipLaunchKernelGGL(k_init, dim3((NNODES + 255) / 256), dim3(256), 0, stream, cnt, stats, gbuf);
    hipLaunchKernelGGL(k_hist, dim3((NEDGES + 255) / 256), dim3(256), 0, stream, dstA, cnt);
    hipLaunchKernelGGL(k_packx, dim3((NNODES * 17 + 255) / 256), dim3(256), 0, stream, x, xb);
    hipLaunchKernelGGL(k_scan1, dim3(SCAN_BLOCKS), dim3(SCAN_TPB), 0, stream, cnt, rowptr, scanBlk, dinv);
    hipLaunchKernelGGL(k_scan2, dim3(1), dim3(64), 0, stream, scanBlk, scanOff);
    hipLaunchKernelGGL(k_scan3, dim3(SCAN_BLOCKS), dim3(SCAN_TPB), 0, stream, rowptr, cursor, scanOff);
    hipLaunchKernelGGL(k_scatter, dim3((NEDGES + 255) / 256), dim3(256), 0, stream,
                       srcA, dstA, dinv, cursor, ew);

    for (int l = 0; l < 4; ++l) {
        float* gs = stats + l * 128;          // + shard*SHSTRIDE inside kernels
        float* gq = stats + 512 + l * 128;
        if (l == 0) {
            hipLaunchKernelGGL((k_aggregate_bf16<17, 36, false>), dim3(12500), dim3(256), 0, stream,
                               xb, Abuf, rowptr, ew, dinv,
                               (const float*)nullptr, (const float*)nullptr,
                               (const float*)nullptr, (const float*)nullptr);
            hipLaunchKernelGGL(k_gemm0, dim3((NNODES + 63) / 64), dim3(256), 0, stream,
                               Abuf, W0, b, Zb, gs, gq);
        } else {
            float* ps = stats + (l - 1) * 128;
            float* pq = stats + 512 + (l - 1) * 128;
            hipLaunchKernelGGL((k_aggregate_bf16<50, CH, true>), dim3(12500), dim3(256), 0, stream,
                               Zb, Abuf, rowptr, ew, dinv,
                               ps, pq, gamma + (l - 1) * CH, beta + (l - 1) * CH);
            hipLaunchKernelGGL((k_gemm<CH, CH, 52>), dim3((NNODES + 63) / 64), dim3(512), 0, stream,
                               Abuf, Wrest + (l - 1) * 10000, b + l * CH, Zb, gs, gq);
        }
    }
    hipLaunchKernelGGL(k_pool, dim3(NGRAPH, 4), dim3(64), 0, stream, Zb, batch,
                       stats + 3 * 128, stats + 512 + 3 * 128, gamma + 3 * CH, beta + 3 * CH, gbuf);
    hipLaunchKernelGGL(k_out, dim3(NGRAPH), dim3(256), 0, stream, gbuf, Wout, bout, out);
}

// Round 16
// 590.455 us; speedup vs baseline: 1.9000x; 1.9000x over previous
//
#include <hip/hip_runtime.h>

#define NNODES 50000
#define NEDGES 800000
#define NGRAPH 500
#define CH 100
#define CIN0 33
#define BN_EPS 1e-5f
#define NSHARD 8
#define SHSTRIDE 1024   // floats per shard: [4 layers][sum128|sq128]

#define SCAN_TPB 256
#define SCAN_IPT 4
#define SCAN_TILE (SCAN_TPB * SCAN_IPT)
#define SCAN_BLOCKS ((NNODES + SCAN_TILE - 1) / SCAN_TILE)

// pack two fp32 into (bf16(x) | bf16(y)<<16), round-to-nearest-even
__device__ inline unsigned pack_bf16(float x, float y) {
    unsigned xb = __float_as_uint(x);
    unsigned yb = __float_as_uint(y);
    xb += 0x7FFF + ((xb >> 16) & 1);
    yb += 0x7FFF + ((yb >> 16) & 1);
    return (xb >> 16) | (yb & 0xFFFF0000u);
}
__device__ inline float unp_lo(unsigned v) { return __uint_as_float(v << 16); }
__device__ inline float unp_hi(unsigned v) { return __uint_as_float(v & 0xFFFF0000u); }

// ---------------- init: zero histogram counters + BN stat shards + pool accumulator ----------------
__global__ void k_init(int* __restrict__ cnt, float* __restrict__ stats,
                       float* __restrict__ gbuf) {
    int i = blockIdx.x * blockDim.x + threadIdx.x;
    if (i < NNODES) cnt[i] = 0;
    if (i < NGRAPH * CH) gbuf[i] = 0.f;   // NGRAPH*CH == NNODES
    if (i < NSHARD * SHSTRIDE) stats[i] = 0.f;
}

// ---------------- in-degree histogram over dst ----------------
__global__ void k_hist(const int* __restrict__ dst, int* __restrict__ cnt) {
    int e = blockIdx.x * blockDim.x + threadIdx.x;
    if (e < NEDGES) atomicAdd(&cnt[dst[e]], 1);
}

// ---------------- pack x (50000 x 33 fp32) into bf16 rows of 17 uints ----------------
__global__ void k_packx(const float* __restrict__ x, unsigned* __restrict__ xb) {
    int i = blockIdx.x * blockDim.x + threadIdx.x;
    if (i >= NNODES * 17) return;
    int r = i / 17, s = i % 17;
    float a = x[r * CIN0 + 2 * s];
    float b = (2 * s + 1 < CIN0) ? x[r * CIN0 + 2 * s + 1] : 0.f;
    xb[i] = pack_bf16(a, b);
}

// ---------------- pack Wrest (3 x 100 x 100 fp32) into bf16: 3 x 100 x 50 uints ----------------
__global__ void k_packw(const float* __restrict__ W, unsigned* __restrict__ wb) {
    int i = blockIdx.x * blockDim.x + threadIdx.x;
    if (i >= 15000) return;                 // 3 * 100 * 50
    int c = i % 50, rl = i / 50;            // rl = l*100 + r
    const float* row = W + rl * 100;
    wb[i] = pack_bf16(row[2 * c], row[2 * c + 1]);
}

// ---------------- exclusive scan of cnt -> rowptr; also dinv = rsqrt(cnt+1) ----------------
__global__ void k_scan1(const int* __restrict__ cnt, int* __restrict__ rowptr,
                        int* __restrict__ blkSums, float* __restrict__ dinv) {
    __shared__ int ts[SCAN_TPB];
    int tid = threadIdx.x;
    int base = blockIdx.x * SCAN_TILE + tid * SCAN_IPT;
    int v[SCAN_IPT];
    int s = 0;
    #pragma unroll
    for (int j = 0; j < SCAN_IPT; ++j) {
        int i = base + j;
        v[j] = (i < NNODES) ? cnt[i] : 0;
        if (i < NNODES) dinv[i] = rsqrtf((float)(v[j] + 1));
        s += v[j];
    }
    ts[tid] = s;
    __syncthreads();
    for (int off = 1; off < SCAN_TPB; off <<= 1) {
        int add = (tid >= off) ? ts[tid - off] : 0;
        __syncthreads();
        ts[tid] += add;
        __syncthreads();
    }
    int run = ts[tid] - s;  // exclusive prefix within block
    #pragma unroll
    for (int j = 0; j < SCAN_IPT; ++j) {
        int i = base + j;
        if (i < NNODES) rowptr[i] = run;
        run += v[j];
    }
    if (tid == SCAN_TPB - 1) blkSums[blockIdx.x] = ts[tid];
}

__global__ void k_scan2(const int* __restrict__ blkSums, int* __restrict__ blkOff) {
    if (threadIdx.x == 0) {
        int run = 0;
        for (int i = 0; i < SCAN_BLOCKS; ++i) { blkOff[i] = run; run += blkSums[i]; }
    }
}

__global__ void k_scan3(int* __restrict__ rowptr, int* __restrict__ cursor,
                        const int* __restrict__ blkOff) {
    int off = blkOff[blockIdx.x];
    int base = blockIdx.x * SCAN_TILE + threadIdx.x * SCAN_IPT;
    #pragma unroll
    for (int j = 0; j < SCAN_IPT; ++j) {
        int i = base + j;
        if (i < NNODES) {
            int vv = rowptr[i] + off;
            rowptr[i] = vv;
            cursor[i] = vv;
        }
    }
    if (blockIdx.x == 0 && threadIdx.x == 0) rowptr[NNODES] = NEDGES;
}

// ---------------- scatter edges into CSR (by dst); pack (src, dinv[src]) ----------------
__global__ void k_scatter(const int* __restrict__ src, const int* __restrict__ dst,
                          const float* __restrict__ dinv, int* __restrict__ cursor,
                          int2* __restrict__ ew) {
    int e = blockIdx.x * blockDim.x + threadIdx.x;
    if (e < NEDGES) {
        int d = dst[e], s = src[e];
        int pos = atomicAdd(&cursor[d], 1);
        ew[pos] = make_int2(s, __float_as_int(dinv[s]));
    }
}

// ---------------- aggregate over bf16-packed rows, fused BN(+ReLU) ----------------
// Input rows: CPACK uints (bf16 pairs). Lane l < CPACK owns channels (2l, 2l+1).
// a[i] = dinv[i]*( sum_e dinv[src]*f(h[src]) + dinv[i]*f(h[i]) ).
// OBF=false: output fp32, row stride OS floats (pad zero-filled).
// OBF=true:  output bf16-packed, row stride OS uints.
template<int CPACK, int OS, bool BN, bool OBF>
__global__ __launch_bounds__(256) void k_aggregate_bf16(
    const unsigned* __restrict__ h, void* __restrict__ aout, const int* __restrict__ rowptr,
    const int2* __restrict__ ew, const float* __restrict__ dinv,
    const float* __restrict__ gsum, const float* __restrict__ gsq,
    const float* __restrict__ gamma, const float* __restrict__ beta) {
    int node = (blockIdx.x * 256 + threadIdx.x) >> 6;
    int lane = threadIdx.x & 63;
    if (node >= NNODES) return;
    int p0 = rowptr[node], p1 = rowptr[node + 1];
    float di = dinv[node];
    constexpr float invN = 1.f / NNODES;
    bool act = lane < CPACK;

    float scx = 0.f, scy = 0.f, shx = 0.f, shy = 0.f;
    if (BN && act) {
        float sx = 0.f, sy = 0.f, qx = 0.f, qy = 0.f;
        #pragma unroll
        for (int sh = 0; sh < NSHARD; ++sh) {
            float2 s2 = ((const float2*)(gsum + sh * SHSTRIDE))[lane];
            float2 q2 = ((const float2*)(gsq + sh * SHSTRIDE))[lane];
            sx += s2.x; sy += s2.y; qx += q2.x; qy += q2.y;
        }
        float2 g2 = ((const float2*)gamma)[lane];
        float2 b2 = ((const float2*)beta)[lane];
        float mx = sx * invN, my = sy * invN;
        float vx = qx * invN - mx * mx, vy = qy * invN - my * my;
        scx = g2.x * rsqrtf(vx + BN_EPS); shx = b2.x - mx * scx;
        scy = g2.y * rsqrtf(vy + BN_EPS); shy = b2.y - my * scy;
    }
    unsigned hvp = 0;
    if (act) hvp = h[(size_t)node * CPACK + lane];

    float ax = 0.f, ay = 0.f;
    for (int base = p0; base < p1; base += 64) {
        int nn = p1 - base; if (nn > 64) nn = 64;
        int2 e = make_int2(0, 0);
        if (lane < nn) e = ew[base + lane];
        int myc = e.x; float myw = __int_as_float(e.y);
        int j = 0;
        for (; j + 16 <= nn; j += 16) {
            int s[16]; float w[16];
            #pragma unroll
            for (int t = 0; t < 16; ++t) { s[t] = __shfl(myc, j + t); w[t] = __shfl(myw, j + t); }
            if (act) {
                unsigned v[16];
                #pragma unroll
                for (int t = 0; t < 16; ++t) v[t] = h[(size_t)s[t] * CPACK + lane];
                #pragma unroll
                for (int t = 0; t < 16; ++t) {
                    float vx = unp_lo(v[t]), vy = unp_hi(v[t]);
                    if (BN) {
                        vx = fmaxf(vx * scx + shx, 0.f);
                        vy = fmaxf(vy * scy + shy, 0.f);
                    }
                    ax += w[t] * vx; ay += w[t] * vy;
                }
            }
        }
        for (; j + 4 <= nn; j += 4) {
            int s[4]; float w[4];
            #pragma unroll
            for (int t = 0; t < 4; ++t) { s[t] = __shfl(myc, j + t); w[t] = __shfl(myw, j + t); }
            if (act) {
                unsigned v[4];
                #pragma unroll
                for (int t = 0; t < 4; ++t) v[t] = h[(size_t)s[t] * CPACK + lane];
                #pragma unroll
                for (int t = 0; t < 4; ++t) {
                    float vx = unp_lo(v[t]), vy = unp_hi(v[t]);
                    if (BN) {
                        vx = fmaxf(vx * scx + shx, 0.f);
                        vy = fmaxf(vy * scy + shy, 0.f);
                    }
                    ax += w[t] * vx; ay += w[t] * vy;
                }
            }
        }
        for (; j < nn; ++j) {
            int s0 = __shfl(myc, j);
            float w0 = __shfl(myw, j);
            if (act) {
                unsigned v = h[(size_t)s0 * CPACK + lane];
                float vx = unp_lo(v), vy = unp_hi(v);
                if (BN) {
                    vx = fmaxf(vx * scx + shx, 0.f);
                    vy = fmaxf(vy * scy + shy, 0.f);
                }
                ax += w0 * vx; ay += w0 * vy;
            }
        }
    }
    float ox = 0.f, oy = 0.f;
    if (act) {
        float hx = unp_lo(hvp), hy = unp_hi(hvp);
        if (BN) {
            hx = fmaxf(hx * scx + shx, 0.f);
            hy = fmaxf(hy * scy + shy, 0.f);
        }
        ox = di * (ax + di * hx);
        oy = di * (ay + di * hy);
    }
    if constexpr (OBF) {
        if (lane < OS)
            ((unsigned*)aout)[(size_t)node * OS + lane] = pack_bf16(ox, oy);
    } else {
        if (lane < (OS + 1) / 2)
            ((float2*)((float*)aout + (size_t)node * OS))[lane] = make_float2(ox, oy);
    }
}

// ---------------- CH-layer GEMM, bf16 LDS (512 thr, 4x4 micro-tile) ----------------
// A (bf16, 50 uints/row) and W (bf16, 100x50 uints) staged as FLAT contiguous
// copies; LDS = 20 KB + 12.8 KB + 0.8 KB = 33.6 KB -> 4 blocks/CU.
// Inner loop: ds_read_b64 + in-register unpack; fp32 accumulate.
__global__ __launch_bounds__(512) void k_gemm_bf(
    const unsigned* __restrict__ Ab, const unsigned* __restrict__ Wb,
    const float* __restrict__ bias, unsigned* __restrict__ Zb,
    float* __restrict__ gsum, float* __restrict__ gsq) {
    __shared__ __align__(16) unsigned wS[CH * 50];   // 20 KB
    __shared__ __align__(16) unsigned aS[64 * 50];   // 12.8 KB
    __shared__ float sSum[CH], sSq[CH];
    int tid = threadIdx.x;
    for (int i = tid; i < CH; i += 512) { sSum[i] = 0.f; sSq[i] = 0.f; }
    for (int i = tid; i < CH * 50; i += 512) wS[i] = Wb[i];
    int row0 = blockIdx.x * 64;
    {
        const unsigned* As = Ab + (size_t)row0 * 50;
        int maxI = (NNODES - row0) * 50;   // >= 3200 except last block
        for (int i = tid; i < 64 * 50; i += 512) aS[i] = (i < maxI) ? As[i] : 0u;
    }
    __syncthreads();
    if (tid < 400) {
        int ct = tid % 25, rt = tid / 25;  // ct 0..24, rt 0..15
        int c0 = ct * 4, cp = ct * 2, r0 = rt * 4;
        float acc[4][4] = {};
        for (int k = 0; k < CH; k += 4) {
            uint2 w0p = *(const uint2*)&wS[(k + 0) * 50 + cp];
            uint2 w1p = *(const uint2*)&wS[(k + 1) * 50 + cp];
            uint2 w2p = *(const uint2*)&wS[(k + 2) * 50 + cp];
            uint2 w3p = *(const uint2*)&wS[(k + 3) * 50 + cp];
            float w00 = unp_lo(w0p.x), w01 = unp_hi(w0p.x), w02 = unp_lo(w0p.y), w03 = unp_hi(w0p.y);
            float w10 = unp_lo(w1p.x), w11 = unp_hi(w1p.x), w12 = unp_lo(w1p.y), w13 = unp_hi(w1p.y);
            float w20 = unp_lo(w2p.x), w21 = unp_hi(w2p.x), w22 = unp_lo(w2p.y), w23 = unp_hi(w2p.y);
            float w30 = unp_lo(w3p.x), w31 = unp_hi(w3p.x), w32 = unp_lo(w3p.y), w33 = unp_hi(w3p.y);
            #pragma unroll
            for (int j = 0; j < 4; ++j) {
                uint2 ap = *(const uint2*)&aS[(r0 + j) * 50 + (k >> 1)];
                float a0 = unp_lo(ap.x), a1 = unp_hi(ap.x), a2 = unp_lo(ap.y), a3 = unp_hi(ap.y);
                acc[j][0] += a0 * w00 + a1 * w10 + a2 * w20 + a3 * w30;
                acc[j][1] += a0 * w01 + a1 * w11 + a2 * w21 + a3 * w31;
                acc[j][2] += a0 * w02 + a1 * w12 + a2 * w22 + a3 * w32;
                acc[j][3] += a0 * w03 + a1 * w13 + a2 * w23 + a3 * w33;
            }
        }
        float4 bv = *(const float4*)&bias[c0];
        float cs0 = 0, cs1 = 0, cs2 = 0, cs3 = 0, cq0 = 0, cq1 = 0, cq2 = 0, cq3 = 0;
        #pragma unroll
        for (int j = 0; j < 4; ++j) {
            int r = row0 + r0 + j;
            if (r < NNODES) {
                float z0 = acc[j][0] + bv.x, z1 = acc[j][1] + bv.y;
                float z2 = acc[j][2] + bv.z, z3 = acc[j][3] + bv.w;
                *(uint2*)&Zb[(size_t)r * 50 + cp] =
                    make_uint2(pack_bf16(z0, z1), pack_bf16(z2, z3));
                cs0 += z0; cs1 += z1; cs2 += z2; cs3 += z3;
                cq0 += z0 * z0; cq1 += z1 * z1; cq2 += z2 * z2; cq3 += z3 * z3;
            }
        }
        atomicAdd(&sSum[c0], cs0); atomicAdd(&sSum[c0 + 1], cs1);
        atomicAdd(&sSum[c0 + 2], cs2); atomicAdd(&sSum[c0 + 3], cs3);
        atomicAdd(&sSq[c0], cq0); atomicAdd(&sSq[c0 + 1], cq1);
        atomicAdd(&sSq[c0 + 2], cq2); atomicAdd(&sSq[c0 + 3], cq3);
    }
    __syncthreads();
    int sh = (blockIdx.x & (NSHARD - 1)) * SHSTRIDE;
    if (tid < CH) { atomicAdd(&gsum[sh + tid], sSum[tid]); atomicAdd(&gsq[sh + tid], sSq[tid]); }
}

// ---------------- layer-0 GEMM (256 thr, 64-row tile, fp32) -> bf16 Z + sharded stats ----------------
// Two sequential 4-row passes (unroll 1) keep only one 4x4 acc set live -> low VGPR.
__global__ __launch_bounds__(256) void k_gemm0(
    const float* __restrict__ A, const float* __restrict__ W, const float* __restrict__ bias,
    unsigned* __restrict__ Zb, float* __restrict__ gsum, float* __restrict__ gsq) {
    constexpr int K = CIN0, KP = 36;
    __shared__ __align__(16) float wS[KP * CH];
    __shared__ __align__(16) float aS[64 * KP];
    __shared__ float sSum[CH], sSq[CH];
    int tid = threadIdx.x;
    for (int i = tid; i < CH; i += 256) { sSum[i] = 0.f; sSq[i] = 0.f; }
    for (int i = tid; i < KP * CH; i += 256) wS[i] = (i < K * CH) ? W[i] : 0.f;
    int row0 = blockIdx.x * 64;
    {
        const float* Ab = A + (size_t)row0 * KP;
        int maxI = (NNODES - row0) * KP;
        for (int i = tid; i < 64 * KP; i += 256) aS[i] = (i < maxI) ? Ab[i] : 0.f;
    }
    __syncthreads();
    if (tid < 200) {
        int ct = tid % 25, rt = tid / 25;  // ct 0..24, rt 0..7
        int c0 = ct * 4;
        float4 bv = *(const float4*)&bias[c0];
        float cs0 = 0, cs1 = 0, cs2 = 0, cs3 = 0, cq0 = 0, cq1 = 0, cq2 = 0, cq3 = 0;
        #pragma unroll 1
        for (int half = 0; half < 2; ++half) {
            int r0 = rt * 8 + half * 4;
            float acc[4][4] = {};
            #pragma unroll
            for (int k = 0; k < KP; k += 4) {
                float4 w0 = *(const float4*)&wS[(k + 0) * CH + c0];
                float4 w1 = *(const float4*)&wS[(k + 1) * CH + c0];
                float4 w2 = *(const float4*)&wS[(k + 2) * CH + c0];
                float4 w3 = *(const float4*)&wS[(k + 3) * CH + c0];
                #pragma unroll
                for (int j = 0; j < 4; ++j) {
                    float4 av = *(const float4*)&aS[(r0 + j) * KP + k];
                    acc[j][0] += av.x * w0.x + av.y * w1.x + av.z * w2.x + av.w * w3.x;
                    acc[j][1] += av.x * w0.y + av.y * w1.y + av.z * w2.y + av.w * w3.y;
                    acc[j][2] += av.x * w0.z + av.y * w1.z + av.z * w2.z + av.w * w3.z;
                    acc[j][3] += av.x * w0.w + av.y * w1.w + av.z * w2.w + av.w * w3.w;
                }
            }
            #pragma unroll
            for (int j = 0; j < 4; ++j) {
                int r = row0 + r0 + j;
                if (r < NNODES) {
                    float z0 = acc[j][0] + bv.x, z1 = acc[j][1] + bv.y;
                    float z2 = acc[j][2] + bv.z, z3 = acc[j][3] + bv.w;
                    *(uint2*)&Zb[(size_t)r * 50 + (c0 >> 1)] =
                        make_uint2(pack_bf16(z0, z1), pack_bf16(z2, z3));
                    cs0 += z0; cs1 += z1; cs2 += z2; cs3 += z3;
                    cq0 += z0 * z0; cq1 += z1 * z1; cq2 += z2 * z2; cq3 += z3 * z3;
                }
            }
        }
        atomicAdd(&sSum[c0], cs0); atomicAdd(&sSum[c0 + 1], cs1);
        atomicAdd(&sSum[c0 + 2], cs2); atomicAdd(&sSum[c0 + 3], cs3);
        atomicAdd(&sSq[c0], cq0); atomicAdd(&sSq[c0 + 1], cq1);
        atomicAdd(&sSq[c0 + 2], cq2); atomicAdd(&sSq[c0 + 3], cq3);
    }
    __syncthreads();
    int sh = (blockIdx.x & (NSHARD - 1)) * SHSTRIDE;
    if (tid < CH) { atomicAdd(&gsum[sh + tid], sSum[tid]); atomicAdd(&gsq[sh + tid], sSq[tid]); }
}

// ---------------- global_add_pool of BN(z) from bf16 Z; 4 row-chunks per graph ----------------
__global__ void k_pool(const unsigned* __restrict__ Zl, const int* __restrict__ batch,
                       const float* __restrict__ gsum, const float* __restrict__ gsq,
                       const float* __restrict__ gamma, const float* __restrict__ beta,
                       float* __restrict__ g) {
    int gid = blockIdx.x;
    int part = blockIdx.y;
    int lo = 0, hi = NNODES;
    while (lo < hi) { int mid = (lo + hi) >> 1; if (batch[mid] < gid) lo = mid + 1; else hi = mid; }
    int start = lo;
    hi = NNODES;
    while (lo < hi) { int mid = (lo + hi) >> 1; if (batch[mid] < gid + 1) lo = mid + 1; else hi = mid; }
    int end = lo;
    int len = end - start;
    int cb = (len + 3) >> 2;
    int s = start + part * cb;
    int e = s + cb; if (e > end) e = end;
    if (s >= e) return;
    int t = threadIdx.x;
    if (t >= 50) return;
    float su = 0.f, sv = 0.f, qu = 0.f, qv = 0.f;
    #pragma unroll
    for (int sh = 0; sh < NSHARD; ++sh) {
        float2 s2 = ((const float2*)(gsum + sh * SHSTRIDE))[t];
        float2 q2 = ((const float2*)(gsq + sh * SHSTRIDE))[t];
        su += s2.x; sv += s2.y; qu += q2.x; qv += q2.y;
    }
    constexpr float invN = 1.f / NNODES;
    float2 g2 = ((const float2*)gamma)[t];
    float2 b2 = ((const float2*)beta)[t];
    float mx = su * invN, my = sv * invN;
    float vx = qu * invN - mx * mx, vy = qv * invN - my * my;
    float scx = g2.x * rsqrtf(vx + BN_EPS), shx = b2.x - mx * scx;
    float scy = g2.y * rsqrtf(vy + BN_EPS), shy = b2.y - my * scy;
    float sx = 0.f, sy = 0.f;
    for (int r = s; r < e; ++r) {
        unsigned v = Zl[(size_t)r * 50 + t];
        sx += unp_lo(v); sy += unp_hi(v);
    }
    float n = (float)(e - s);
    atomicAdd(&g[gid * CH + 2 * t], sx * scx + n * shx);
    atomicAdd(&g[gid * CH + 2 * t + 1], sy * scy + n * shy);
}

// ---------------- out = leakyrelu(g @ Wout + bout, 0.1) ----------------
__global__ __launch_bounds__(256) void k_out(const float* __restrict__ g,
                                             const float* __restrict__ Wout,
                                             const float* __restrict__ bout,
                                             float* __restrict__ out) {
    __shared__ float gS[CH];
    int gid = blockIdx.x, tid = threadIdx.x;
    if (tid < CH) gS[tid] = g[gid * CH + tid];
    __syncthreads();
    if (tid >= 200) return;
    float acc = bout[tid];
    for (int k = 0; k < CH; ++k) acc += gS[k] * Wout[k * 200 + tid];
    out[gid * 200 + tid] = acc > 0.f ? acc : 0.1f * acc;
}

extern "C" void kernel_launch(void* const* d_in, const int* in_sizes, int n_in,
                              void* d_out, int out_size, void* d_ws, size_t ws_size,
                              hipStream_t stream) {
    const float* x = (const float*)d_in[0];
    const int* ei = (const int*)d_in[1];
    const int* batch = (const int*)d_in[2];
    const float* W0 = (const float*)d_in[3];
    const float* Wrest = (const float*)d_in[4];
    const float* b = (const float*)d_in[5];
    const float* gamma = (const float*)d_in[6];
    const float* beta = (const float*)d_in[7];
    const float* Wout = (const float*)d_in[8];
    const float* bout = (const float*)d_in[9];
    float* out = (float*)d_out;
    const int* srcA = ei;
    const int* dstA = ei + NEDGES;

    char* wsb = (char*)d_ws;
    size_t off = 0;
    auto alloc = [&](size_t elems) -> void* {
        void* p = (void*)(wsb + off);
        off += ((elems + 7) & ~(size_t)7) * 4;
        return p;
    };
    int* cnt = (int*)alloc(NNODES);
    int* rowptr = (int*)alloc(NNODES + 1);
    int* cursor = (int*)alloc(NNODES);
    float* dinv = (float*)alloc(NNODES);
    int* scanBlk = (int*)alloc(64);
    int* scanOff = (int*)alloc(64);
    float* stats = (float*)alloc(NSHARD * SHSTRIDE);  // per shard: [l*128]=sum, [512+l*128]=sq
    int2* ew = (int2*)alloc(2 * (size_t)NEDGES);
    unsigned* xb = (unsigned*)alloc((size_t)NNODES * 17);
    unsigned* Wb = (unsigned*)alloc(15000);
    float* A0 = (float*)alloc((size_t)NNODES * 36);
    unsigned* Abf = (unsigned*)alloc((size_t)NNODES * 50);
    unsigned* Zb = (unsigned*)alloc((size_t)NNODES * 50);
    float* gbuf = (float*)alloc((size_t)NGRAPH * CH);
    (void)ws_size; (void)n_in; (void)in_sizes; (void)out_size;

    hipLaunchKernelGGL(k_init, dim3((NNODES + 255) / 256), dim3(256), 0, stream, cnt, stats, gbuf);
    hipLaunchKernelGGL(k_hist, dim3((NEDGES + 255) / 256), dim3(256), 0, stream, dstA, cnt);
    hipLaunchKernelGGL(k_packx, dim3((NNODES * 17 + 255) / 256), dim3(256), 0, stream, x, xb);
    hipLaunchKernelGGL(k_packw, dim3((15000 + 255) / 256), dim3(256), 0, stream, Wrest, Wb);
    hipLaunchKernelGGL(k_scan1, dim3(SCAN_BLOCKS), dim3(SCAN_TPB), 0, stream, cnt, rowptr, scanBlk, dinv);
    hipLaunchKernelGGL(k_scan2, dim3(1), dim3(64), 0, stream, scanBlk, scanOff);
    hipLaunchKernelGGL(k_scan3, dim3(SCAN_BLOCKS), dim3(SCAN_TPB), 0, stream, rowptr, cursor, scanOff);
    hipLaunchKernelGGL(k_scatter, dim3((NEDGES + 255) / 256), dim3(256), 0, stream,
                       srcA, dstA, dinv, cursor, ew);

    for (int l = 0; l < 4; ++l) {
        float* gs = stats + l * 128;          // + shard*SHSTRIDE inside kernels
        float* gq = stats + 512 + l * 128;
        if (l == 0) {
            hipLaunchKernelGGL((k_aggregate_bf16<17, 36, false, false>), dim3(12500), dim3(256), 0,
                               stream, xb, A0, rowptr, ew, dinv,
                               (const float*)nullptr, (const float*)nullptr,
                               (const float*)nullptr, (const float*)nullptr);
            hipLaunchKernelGGL(k_gemm0, dim3((NNODES + 63) / 64), dim3(256), 0, stream,
                               A0, W0, b, Zb, gs, gq);
        } else {
            float* ps = stats + (l - 1) * 128;
            float* pq = stats + 512 + (l - 1) * 128;
            hipLaunchKernelGGL((k_aggregate_bf16<50, 50, true, true>), dim3(12500), dim3(256), 0,
                               stream, Zb, Abf, rowptr, ew, dinv,
                               ps, pq, gamma + (l - 1) * CH, beta + (l - 1) * CH);
            hipLaunchKernelGGL(k_gemm_bf, dim3((NNODES + 63) / 64), dim3(512), 0, stream,
                               Abf, Wb + (l - 1) * 5000, b + l * CH, Zb, gs, gq);
        }
    }
    hipLaunchKernelGGL(k_pool, dim3(NGRAPH, 4), dim3(64), 0, stream, Zb, batch,
                       stats + 3 * 128, stats + 512 + 3 * 128, gamma + 3 * CH, beta + 3 * CH, gbuf);
    hipLaunchKernelGGL(k_out, dim3(NGRAPH), dim3(256), 0, stream, gbuf, Wout, bout, out);
}

// Round 17
// 560.685 us; speedup vs baseline: 2.0009x; 1.0531x over previous
//
#include <hip/hip_runtime.h>

#define NNODES 50000
#define NEDGES 800000
#define NGRAPH 500
#define CH 100
#define CIN0 33
#define BN_EPS 1e-5f
#define NSHARD 8
#define SHSTRIDE 1024   // floats per shard: [4 layers][sum128|sq128]

#define SCAN_TPB 256
#define SCAN_IPT 4
#define SCAN_TILE (SCAN_TPB * SCAN_IPT)
#define SCAN_BLOCKS ((NNODES + SCAN_TILE - 1) / SCAN_TILE)

// pack two fp32 into (bf16(x) | bf16(y)<<16), round-to-nearest-even
__device__ inline unsigned pack_bf16(float x, float y) {
    unsigned xb = __float_as_uint(x);
    unsigned yb = __float_as_uint(y);
    xb += 0x7FFF + ((xb >> 16) & 1);
    yb += 0x7FFF + ((yb >> 16) & 1);
    return (xb >> 16) | (yb & 0xFFFF0000u);
}
__device__ inline float unp_lo(unsigned v) { return __uint_as_float(v << 16); }
__device__ inline float unp_hi(unsigned v) { return __uint_as_float(v & 0xFFFF0000u); }

// ---------------- init: zero histogram counters + BN stat shards + pool accumulator ----------------
__global__ void k_init(int* __restrict__ cnt, float* __restrict__ stats,
                       float* __restrict__ gbuf) {
    int i = blockIdx.x * blockDim.x + threadIdx.x;
    if (i < NNODES) cnt[i] = 0;
    if (i < NGRAPH * CH) gbuf[i] = 0.f;   // NGRAPH*CH == NNODES
    if (i < NSHARD * SHSTRIDE) stats[i] = 0.f;
}

// ---------------- in-degree histogram over dst ----------------
__global__ void k_hist(const int* __restrict__ dst, int* __restrict__ cnt) {
    int e = blockIdx.x * blockDim.x + threadIdx.x;
    if (e < NEDGES) atomicAdd(&cnt[dst[e]], 1);
}

// ---------------- pack x (50000 x 33 fp32) into bf16 rows of 17 uints ----------------
__global__ void k_packx(const float* __restrict__ x, unsigned* __restrict__ xb) {
    int i = blockIdx.x * blockDim.x + threadIdx.x;
    if (i >= NNODES * 17) return;
    int r = i / 17, s = i % 17;
    float a = x[r * CIN0 + 2 * s];
    float b = (2 * s + 1 < CIN0) ? x[r * CIN0 + 2 * s + 1] : 0.f;
    xb[i] = pack_bf16(a, b);
}

// ---------------- pack Wrest (3 x 100 x 100 fp32) into bf16: 3 x 100 x 50 uints ----------------
__global__ void k_packw(const float* __restrict__ W, unsigned* __restrict__ wb) {
    int i = blockIdx.x * blockDim.x + threadIdx.x;
    if (i >= 15000) return;                 // 3 * 100 * 50
    int c = i % 50, rl = i / 50;            // rl = l*100 + r
    const float* row = W + rl * 100;
    wb[i] = pack_bf16(row[2 * c], row[2 * c + 1]);
}

// ---------------- exclusive scan of cnt -> rowptr; also dinv = rsqrt(cnt+1) ----------------
__global__ void k_scan1(const int* __restrict__ cnt, int* __restrict__ rowptr,
                        int* __restrict__ blkSums, float* __restrict__ dinv) {
    __shared__ int ts[SCAN_TPB];
    int tid = threadIdx.x;
    int base = blockIdx.x * SCAN_TILE + tid * SCAN_IPT;
    int v[SCAN_IPT];
    int s = 0;
    #pragma unroll
    for (int j = 0; j < SCAN_IPT; ++j) {
        int i = base + j;
        v[j] = (i < NNODES) ? cnt[i] : 0;
        if (i < NNODES) dinv[i] = rsqrtf((float)(v[j] + 1));
        s += v[j];
    }
    ts[tid] = s;
    __syncthreads();
    for (int off = 1; off < SCAN_TPB; off <<= 1) {
        int add = (tid >= off) ? ts[tid - off] : 0;
        __syncthreads();
        ts[tid] += add;
        __syncthreads();
    }
    int run = ts[tid] - s;  // exclusive prefix within block
    #pragma unroll
    for (int j = 0; j < SCAN_IPT; ++j) {
        int i = base + j;
        if (i < NNODES) rowptr[i] = run;
        run += v[j];
    }
    if (tid == SCAN_TPB - 1) blkSums[blockIdx.x] = ts[tid];
}

__global__ void k_scan2(const int* __restrict__ blkSums, int* __restrict__ blkOff) {
    if (threadIdx.x == 0) {
        int run = 0;
        for (int i = 0; i < SCAN_BLOCKS; ++i) { blkOff[i] = run; run += blkSums[i]; }
    }
}

__global__ void k_scan3(int* __restrict__ rowptr, int* __restrict__ cursor,
                        const int* __restrict__ blkOff) {
    int off = blkOff[blockIdx.x];
    int base = blockIdx.x * SCAN_TILE + threadIdx.x * SCAN_IPT;
    #pragma unroll
    for (int j = 0; j < SCAN_IPT; ++j) {
        int i = base + j;
        if (i < NNODES) {
            int vv = rowptr[i] + off;
            rowptr[i] = vv;
            cursor[i] = vv;
        }
    }
    if (blockIdx.x == 0 && threadIdx.x == 0) rowptr[NNODES] = NEDGES;
}

// ---------------- scatter edges into CSR (by dst); pack (src, dinv[src]) ----------------
__global__ void k_scatter(const int* __restrict__ src, const int* __restrict__ dst,
                          const float* __restrict__ dinv, int* __restrict__ cursor,
                          int2* __restrict__ ew) {
    int e = blockIdx.x * blockDim.x + threadIdx.x;
    if (e < NEDGES) {
        int d = dst[e], s = src[e];
        int pos = atomicAdd(&cursor[d], 1);
        ew[pos] = make_int2(s, __float_as_int(dinv[s]));
    }
}

// ---------------- aggregate over bf16-packed rows, fused BN(+ReLU); fp32 output ----------------
// Input rows: CPACK uints (bf16 pairs). Lane l < CPACK owns channels (2l, 2l+1).
// a[i] = dinv[i]*( sum_e dinv[src]*f(h[src]) + dinv[i]*f(h[i]) ).
// Output fp32, row stride OS floats; pad pairs zero-filled.
template<int CPACK, int OS, bool BN>
__global__ __launch_bounds__(256) void k_aggregate_bf16(
    const unsigned* __restrict__ h, float* __restrict__ a, const int* __restrict__ rowptr,
    const int2* __restrict__ ew, const float* __restrict__ dinv,
    const float* __restrict__ gsum, const float* __restrict__ gsq,
    const float* __restrict__ gamma, const float* __restrict__ beta) {
    int node = (blockIdx.x * 256 + threadIdx.x) >> 6;
    int lane = threadIdx.x & 63;
    if (node >= NNODES) return;
    int p0 = rowptr[node], p1 = rowptr[node + 1];
    float di = dinv[node];
    constexpr float invN = 1.f / NNODES;
    bool act = lane < CPACK;

    float scx = 0.f, scy = 0.f, shx = 0.f, shy = 0.f;
    if (BN && act) {
        float sx = 0.f, sy = 0.f, qx = 0.f, qy = 0.f;
        #pragma unroll
        for (int sh = 0; sh < NSHARD; ++sh) {
            float2 s2 = ((const float2*)(gsum + sh * SHSTRIDE))[lane];
            float2 q2 = ((const float2*)(gsq + sh * SHSTRIDE))[lane];
            sx += s2.x; sy += s2.y; qx += q2.x; qy += q2.y;
        }
        float2 g2 = ((const float2*)gamma)[lane];
        float2 b2 = ((const float2*)beta)[lane];
        float mx = sx * invN, my = sy * invN;
        float vx = qx * invN - mx * mx, vy = qy * invN - my * my;
        scx = g2.x * rsqrtf(vx + BN_EPS); shx = b2.x - mx * scx;
        scy = g2.y * rsqrtf(vy + BN_EPS); shy = b2.y - my * scy;
    }
    unsigned hvp = 0;
    if (act) hvp = h[(size_t)node * CPACK + lane];

    float ax = 0.f, ay = 0.f;
    for (int base = p0; base < p1; base += 64) {
        int nn = p1 - base; if (nn > 64) nn = 64;
        int2 e = make_int2(0, 0);
        if (lane < nn) e = ew[base + lane];
        int myc = e.x; float myw = __int_as_float(e.y);
        int j = 0;
        for (; j + 16 <= nn; j += 16) {
            int s[16]; float w[16];
            #pragma unroll
            for (int t = 0; t < 16; ++t) { s[t] = __shfl(myc, j + t); w[t] = __shfl(myw, j + t); }
            if (act) {
                unsigned v[16];
                #pragma unroll
                for (int t = 0; t < 16; ++t) v[t] = h[(size_t)s[t] * CPACK + lane];
                #pragma unroll
                for (int t = 0; t < 16; ++t) {
                    float vx = unp_lo(v[t]), vy = unp_hi(v[t]);
                    if (BN) {
                        vx = fmaxf(vx * scx + shx, 0.f);
                        vy = fmaxf(vy * scy + shy, 0.f);
                    }
                    ax += w[t] * vx; ay += w[t] * vy;
                }
            }
        }
        for (; j + 4 <= nn; j += 4) {
            int s[4]; float w[4];
            #pragma unroll
            for (int t = 0; t < 4; ++t) { s[t] = __shfl(myc, j + t); w[t] = __shfl(myw, j + t); }
            if (act) {
                unsigned v[4];
                #pragma unroll
                for (int t = 0; t < 4; ++t) v[t] = h[(size_t)s[t] * CPACK + lane];
                #pragma unroll
                for (int t = 0; t < 4; ++t) {
                    float vx = unp_lo(v[t]), vy = unp_hi(v[t]);
                    if (BN) {
                        vx = fmaxf(vx * scx + shx, 0.f);
                        vy = fmaxf(vy * scy + shy, 0.f);
                    }
                    ax += w[t] * vx; ay += w[t] * vy;
                }
            }
        }
        for (; j < nn; ++j) {
            int s0 = __shfl(myc, j);
            float w0 = __shfl(myw, j);
            if (act) {
                unsigned v = h[(size_t)s0 * CPACK + lane];
                float vx = unp_lo(v), vy = unp_hi(v);
                if (BN) {
                    vx = fmaxf(vx * scx + shx, 0.f);
                    vy = fmaxf(vy * scy + shy, 0.f);
                }
                ax += w0 * vx; ay += w0 * vy;
            }
        }
    }
    if (lane < (OS + 1) / 2) {
        float2 o = make_float2(0.f, 0.f);
        if (act) {
            float hx = unp_lo(hvp), hy = unp_hi(hvp);
            if (BN) {
                hx = fmaxf(hx * scx + shx, 0.f);
                hy = fmaxf(hy * scy + shy, 0.f);
            }
            o.x = di * (ax + di * hx);
            o.y = di * (ay + di * hy);
        }
        ((float2*)(a + (size_t)node * OS))[lane] = o;
    }
}

// ---------------- CH-layer GEMM: A fp32 LDS + W bf16 LDS (512 thr, 4x4 tile) ----------------
// LDS = 20 KB (W bf16) + 25.6 KB (A fp32) + 0.8 KB = 46.4 KB -> 3 blocks/CU.
// A reads are R14's exact b128 path (no unpack on the hot operand); W unpack
// amortizes over 4 rows (+16 VALU per 64 FMA). Flat contiguous staging only.
__global__ __launch_bounds__(512) void k_gemm_hy(
    const float* __restrict__ A, const unsigned* __restrict__ Wb,
    const float* __restrict__ bias, unsigned* __restrict__ Zb,
    float* __restrict__ gsum, float* __restrict__ gsq) {
    __shared__ __align__(16) unsigned wS[CH * 50];   // 20 KB, W[k][c] bf16 pairs (c-packed)
    __shared__ __align__(16) float aS[64 * CH];      // 25.6 KB
    __shared__ float sSum[CH], sSq[CH];
    int tid = threadIdx.x;
    for (int i = tid; i < CH; i += 512) { sSum[i] = 0.f; sSq[i] = 0.f; }
    for (int i = tid; i < CH * 50; i += 512) wS[i] = Wb[i];
    int row0 = blockIdx.x * 64;
    {
        const float* As = A + (size_t)row0 * CH;
        int maxI = (NNODES - row0) * CH;   // >= 6400 except last block
        for (int i = tid; i < 64 * CH; i += 512) aS[i] = (i < maxI) ? As[i] : 0.f;
    }
    __syncthreads();
    if (tid < 400) {
        int ct = tid % 25, rt = tid / 25;  // ct 0..24, rt 0..15
        int c0 = ct * 4, cp = ct * 2, r0 = rt * 4;
        float acc[4][4] = {};
        for (int k = 0; k < CH; k += 4) {
            uint2 w0p = *(const uint2*)&wS[(k + 0) * 50 + cp];
            uint2 w1p = *(const uint2*)&wS[(k + 1) * 50 + cp];
            uint2 w2p = *(const uint2*)&wS[(k + 2) * 50 + cp];
            uint2 w3p = *(const uint2*)&wS[(k + 3) * 50 + cp];
            float w00 = unp_lo(w0p.x), w01 = unp_hi(w0p.x), w02 = unp_lo(w0p.y), w03 = unp_hi(w0p.y);
            float w10 = unp_lo(w1p.x), w11 = unp_hi(w1p.x), w12 = unp_lo(w1p.y), w13 = unp_hi(w1p.y);
            float w20 = unp_lo(w2p.x), w21 = unp_hi(w2p.x), w22 = unp_lo(w2p.y), w23 = unp_hi(w2p.y);
            float w30 = unp_lo(w3p.x), w31 = unp_hi(w3p.x), w32 = unp_lo(w3p.y), w33 = unp_hi(w3p.y);
            #pragma unroll
            for (int j = 0; j < 4; ++j) {
                float4 av = *(const float4*)&aS[(r0 + j) * CH + k];
                acc[j][0] += av.x * w00 + av.y * w10 + av.z * w20 + av.w * w30;
                acc[j][1] += av.x * w01 + av.y * w11 + av.z * w21 + av.w * w31;
                acc[j][2] += av.x * w02 + av.y * w12 + av.z * w22 + av.w * w32;
                acc[j][3] += av.x * w03 + av.y * w13 + av.z * w23 + av.w * w33;
            }
        }
        float4 bv = *(const float4*)&bias[c0];
        float cs0 = 0, cs1 = 0, cs2 = 0, cs3 = 0, cq0 = 0, cq1 = 0, cq2 = 0, cq3 = 0;
        #pragma unroll
        for (int j = 0; j < 4; ++j) {
            int r = row0 + r0 + j;
            if (r < NNODES) {
                float z0 = acc[j][0] + bv.x, z1 = acc[j][1] + bv.y;
                float z2 = acc[j][2] + bv.z, z3 = acc[j][3] + bv.w;
                *(uint2*)&Zb[(size_t)r * 50 + cp] =
                    make_uint2(pack_bf16(z0, z1), pack_bf16(z2, z3));
                cs0 += z0; cs1 += z1; cs2 += z2; cs3 += z3;
                cq0 += z0 * z0; cq1 += z1 * z1; cq2 += z2 * z2; cq3 += z3 * z3;
            }
        }
        atomicAdd(&sSum[c0], cs0); atomicAdd(&sSum[c0 + 1], cs1);
        atomicAdd(&sSum[c0 + 2], cs2); atomicAdd(&sSum[c0 + 3], cs3);
        atomicAdd(&sSq[c0], cq0); atomicAdd(&sSq[c0 + 1], cq1);
        atomicAdd(&sSq[c0 + 2], cq2); atomicAdd(&sSq[c0 + 3], cq3);
    }
    __syncthreads();
    int sh = (blockIdx.x & (NSHARD - 1)) * SHSTRIDE;
    if (tid < CH) { atomicAdd(&gsum[sh + tid], sSum[tid]); atomicAdd(&gsq[sh + tid], sSq[tid]); }
}

// ---------------- layer-0 GEMM (256 thr, 64-row tile, fp32) -> bf16 Z + sharded stats ----------------
// Two sequential 4-row passes (unroll 1) keep only one 4x4 acc set live -> low VGPR.
__global__ __launch_bounds__(256) void k_gemm0(
    const float* __restrict__ A, const float* __restrict__ W, const float* __restrict__ bias,
    unsigned* __restrict__ Zb, float* __restrict__ gsum, float* __restrict__ gsq) {
    constexpr int K = CIN0, KP = 36;
    __shared__ __align__(16) float wS[KP * CH];
    __shared__ __align__(16) float aS[64 * KP];
    __shared__ float sSum[CH], sSq[CH];
    int tid = threadIdx.x;
    for (int i = tid; i < CH; i += 256) { sSum[i] = 0.f; sSq[i] = 0.f; }
    for (int i = tid; i < KP * CH; i += 256) wS[i] = (i < K * CH) ? W[i] : 0.f;
    int row0 = blockIdx.x * 64;
    {
        const float* Ab = A + (size_t)row0 * KP;
        int maxI = (NNODES - row0) * KP;
        for (int i = tid; i < 64 * KP; i += 256) aS[i] = (i < maxI) ? Ab[i] : 0.f;
    }
    __syncthreads();
    if (tid < 200) {
        int ct = tid % 25, rt = tid / 25;  // ct 0..24, rt 0..7
        int c0 = ct * 4;
        float4 bv = *(const float4*)&bias[c0];
        float cs0 = 0, cs1 = 0, cs2 = 0, cs3 = 0, cq0 = 0, cq1 = 0, cq2 = 0, cq3 = 0;
        #pragma unroll 1
        for (int half = 0; half < 2; ++half) {
            int r0 = rt * 8 + half * 4;
            float acc[4][4] = {};
            #pragma unroll
            for (int k = 0; k < KP; k += 4) {
                float4 w0 = *(const float4*)&wS[(k + 0) * CH + c0];
                float4 w1 = *(const float4*)&wS[(k + 1) * CH + c0];
                float4 w2 = *(const float4*)&wS[(k + 2) * CH + c0];
                float4 w3 = *(const float4*)&wS[(k + 3) * CH + c0];
                #pragma unroll
                for (int j = 0; j < 4; ++j) {
                    float4 av = *(const float4*)&aS[(r0 + j) * KP + k];
                    acc[j][0] += av.x * w0.x + av.y * w1.x + av.z * w2.x + av.w * w3.x;
                    acc[j][1] += av.x * w0.y + av.y * w1.y + av.z * w2.y + av.w * w3.y;
                    acc[j][2] += av.x * w0.z + av.y * w1.z + av.z * w2.z + av.w * w3.z;
                    acc[j][3] += av.x * w0.w + av.y * w1.w + av.z * w2.w + av.w * w3.w;
                }
            }
            #pragma unroll
            for (int j = 0; j < 4; ++j) {
                int r = row0 + r0 + j;
                if (r < NNODES) {
                    float z0 = acc[j][0] + bv.x, z1 = acc[j][1] + bv.y;
                    float z2 = acc[j][2] + bv.z, z3 = acc[j][3] + bv.w;
                    *(uint2*)&Zb[(size_t)r * 50 + (c0 >> 1)] =
                        make_uint2(pack_bf16(z0, z1), pack_bf16(z2, z3));
                    cs0 += z0; cs1 += z1; cs2 += z2; cs3 += z3;
                    cq0 += z0 * z0; cq1 += z1 * z1; cq2 += z2 * z2; cq3 += z3 * z3;
                }
            }
        }
        atomicAdd(&sSum[c0], cs0); atomicAdd(&sSum[c0 + 1], cs1);
        atomicAdd(&sSum[c0 + 2], cs2); atomicAdd(&sSum[c0 + 3], cs3);
        atomicAdd(&sSq[c0], cq0); atomicAdd(&sSq[c0 + 1], cq1);
        atomicAdd(&sSq[c0 + 2], cq2); atomicAdd(&sSq[c0 + 3], cq3);
    }
    __syncthreads();
    int sh = (blockIdx.x & (NSHARD - 1)) * SHSTRIDE;
    if (tid < CH) { atomicAdd(&gsum[sh + tid], sSum[tid]); atomicAdd(&gsq[sh + tid], sSq[tid]); }
}

// ---------------- global_add_pool of BN(z) from bf16 Z; 4 row-chunks per graph ----------------
__global__ void k_pool(const unsigned* __restrict__ Zl, const int* __restrict__ batch,
                       const float* __restrict__ gsum, const float* __restrict__ gsq,
                       const float* __restrict__ gamma, const float* __restrict__ beta,
                       float* __restrict__ g) {
    int gid = blockIdx.x;
    int part = blockIdx.y;
    int lo = 0, hi = NNODES;
    while (lo < hi) { int mid = (lo + hi) >> 1; if (batch[mid] < gid) lo = mid + 1; else hi = mid; }
    int start = lo;
    hi = NNODES;
    while (lo < hi) { int mid = (lo + hi) >> 1; if (batch[mid] < gid + 1) lo = mid + 1; else hi = mid; }
    int end = lo;
    int len = end - start;
    int cb = (len + 3) >> 2;
    int s = start + part * cb;
    int e = s + cb; if (e > end) e = end;
    if (s >= e) return;
    int t = threadIdx.x;
    if (t >= 50) return;
    float su = 0.f, sv = 0.f, qu = 0.f, qv = 0.f;
    #pragma unroll
    for (int sh = 0; sh < NSHARD; ++sh) {
        float2 s2 = ((const float2*)(gsum + sh * SHSTRIDE))[t];
        float2 q2 = ((const float2*)(gsq + sh * SHSTRIDE))[t];
        su += s2.x; sv += s2.y; qu += q2.x; qv += q2.y;
    }
    constexpr float invN = 1.f / NNODES;
    float2 g2 = ((const float2*)gamma)[t];
    float2 b2 = ((const float2*)beta)[t];
    float mx = su * invN, my = sv * invN;
    float vx = qu * invN - mx * mx, vy = qv * invN - my * my;
    float scx = g2.x * rsqrtf(vx + BN_EPS), shx = b2.x - mx * scx;
    float scy = g2.y * rsqrtf(vy + BN_EPS), shy = b2.y - my * scy;
    float sx = 0.f, sy = 0.f;
    for (int r = s; r < e; ++r) {
        unsigned v = Zl[(size_t)r * 50 + t];
        sx += unp_lo(v); sy += unp_hi(v);
    }
    float n = (float)(e - s);
    atomicAdd(&g[gid * CH + 2 * t], sx * scx + n * shx);
    atomicAdd(&g[gid * CH + 2 * t + 1], sy * scy + n * shy);
}

// ---------------- out = leakyrelu(g @ Wout + bout, 0.1) ----------------
__global__ __launch_bounds__(256) void k_out(const float* __restrict__ g,
                                             const float* __restrict__ Wout,
                                             const float* __restrict__ bout,
                                             float* __restrict__ out) {
    __shared__ float gS[CH];
    int gid = blockIdx.x, tid = threadIdx.x;
    if (tid < CH) gS[tid] = g[gid * CH + tid];
    __syncthreads();
    if (tid >= 200) return;
    float acc = bout[tid];
    for (int k = 0; k < CH; ++k) acc += gS[k] * Wout[k * 200 + tid];
    out[gid * 200 + tid] = acc > 0.f ? acc : 0.1f * acc;
}

extern "C" void kernel_launch(void* const* d_in, const int* in_sizes, int n_in,
                              void* d_out, int out_size, void* d_ws, size_t ws_size,
                              hipStream_t stream) {
    const float* x = (const float*)d_in[0];
    const int* ei = (const int*)d_in[1];
    const int* batch = (const int*)d_in[2];
    const float* W0 = (const float*)d_in[3];
    const float* Wrest = (const float*)d_in[4];
    const float* b = (const float*)d_in[5];
    const float* gamma = (const float*)d_in[6];
    const float* beta = (const float*)d_in[7];
    const float* Wout = (const float*)d_in[8];
    const float* bout = (const float*)d_in[9];
    float* out = (float*)d_out;
    const int* srcA = ei;
    const int* dstA = ei + NEDGES;

    char* wsb = (char*)d_ws;
    size_t off = 0;
    auto alloc = [&](size_t elems) -> void* {
        void* p = (void*)(wsb + off);
        off += ((elems + 7) & ~(size_t)7) * 4;
        return p;
    };
    int* cnt = (int*)alloc(NNODES);
    int* rowptr = (int*)alloc(NNODES + 1);
    int* cursor = (int*)alloc(NNODES);
    float* dinv = (float*)alloc(NNODES);
    int* scanBlk = (int*)alloc(64);
    int* scanOff = (int*)alloc(64);
    float* stats = (float*)alloc(NSHARD * SHSTRIDE);  // per shard: [l*128]=sum, [512+l*128]=sq
    int2* ew = (int2*)alloc(2 * (size_t)NEDGES);
    unsigned* xb = (unsigned*)alloc((size_t)NNODES * 17);
    unsigned* Wb = (unsigned*)alloc(15000);
    float* Abuf = (float*)alloc((size_t)NNODES * CH);
    unsigned* Zb = (unsigned*)alloc((size_t)NNODES * 50);
    float* gbuf = (float*)alloc((size_t)NGRAPH * CH);
    (void)ws_size; (void)n_in; (void)in_sizes; (void)out_size;

    hipLaunchKernelGGL(k_init, dim3((NNODES + 255) / 256), dim3(256), 0, stream, cnt, stats, gbuf);
    hipLaunchKernelGGL(k_hist, dim3((NEDGES + 255) / 256), dim3(256), 0, stream, dstA, cnt);
    hipLaunchKernelGGL(k_packx, dim3((NNODES * 17 + 255) / 256), dim3(256), 0, stream, x, xb);
    hipLaunchKernelGGL(k_packw, dim3((15000 + 255) / 256), dim3(256), 0, stream, Wrest, Wb);
    hipLaunchKernelGGL(k_scan1, dim3(SCAN_BLOCKS), dim3(SCAN_TPB), 0, stream, cnt, rowptr, scanBlk, dinv);
    hipLaunchKernelGGL(k_scan2, dim3(1), dim3(64), 0, stream, scanBlk, scanOff);
    hipLaunchKernelGGL(k_scan3, dim3(SCAN_BLOCKS), dim3(SCAN_TPB), 0, stream, rowptr, cursor, scanOff);
    hipLaunchKernelGGL(k_scatter, dim3((NEDGES + 255) / 256), dim3(256), 0, stream,
                       srcA, dstA, dinv, cursor, ew);

    for (int l = 0; l < 4; ++l) {
        float* gs = stats + l * 128;          // + shard*SHSTRIDE inside kernels
        float* gq = stats + 512 + l * 128;
        if (l == 0) {
            hipLaunchKernelGGL((k_aggregate_bf16<17, 36, false>), dim3(12500), dim3(256), 0, stream,
                               xb, Abuf, rowptr, ew, dinv,
                               (const float*)nullptr, (const float*)nullptr,
                               (const float*)nullptr, (const float*)nullptr);
            hipLaunchKernelGGL(k_gemm0, dim3((NNODES + 63) / 64), dim3(256), 0, stream,
                               Abuf, W0, b, Zb, gs, gq);
        } else {
            float* ps = stats + (l - 1) * 128;
            float* pq = stats + 512 + (l - 1) * 128;
            hipLaunchKernelGGL((k_aggregate_bf16<50, CH, true>), dim3(12500), dim3(256), 0, stream,
                               Zb, Abuf, rowptr, ew, dinv,
                               ps, pq, gamma + (l - 1) * CH, beta + (l - 1) * CH);
            hipLaunchKernelGGL(k_gemm_hy, dim3((NNODES + 63) / 64), dim3(512), 0, stream,
                               Abuf, Wb + (l - 1) * 5000, b + l * CH, Zb, gs, gq);
        }
    }
    hipLaunchKernelGGL(k_pool, dim3(NGRAPH, 4), dim3(64), 0, stream, Zb, batch,
                       stats + 3 * 128, stats + 512 + 3 * 128, gamma + 3 * CH, beta + 3 * CH, gbuf);
    hipLaunchKernelGGL(k_out, dim3(NGRAPH), dim3(256), 0, stream, gbuf, Wout, bout, out);
}

// Round 18
// 541.370 us; speedup vs baseline: 2.0723x; 1.0357x over previous
//
#include <hip/hip_runtime.h>

#define NNODES 50000
#define NEDGES 800000
#define NGRAPH 500
#define CH 100
#define CIN0 33
#define BN_EPS 1e-5f
#define NSHARD 8
#define SHSTRIDE 1024   // floats per shard: [4 layers][sum128|sq128]

#define SCAN_TPB 256
#define SCAN_IPT 4
#define SCAN_TILE (SCAN_TPB * SCAN_IPT)
#define SCAN_BLOCKS ((NNODES + SCAN_TILE - 1) / SCAN_TILE)

// pack two fp32 into (bf16(x) | bf16(y)<<16), round-to-nearest-even
__device__ inline unsigned pack_bf16(float x, float y) {
    unsigned xb = __float_as_uint(x);
    unsigned yb = __float_as_uint(y);
    xb += 0x7FFF + ((xb >> 16) & 1);
    yb += 0x7FFF + ((yb >> 16) & 1);
    return (xb >> 16) | (yb & 0xFFFF0000u);
}
__device__ inline float unp_lo(unsigned v) { return __uint_as_float(v << 16); }
__device__ inline float unp_hi(unsigned v) { return __uint_as_float(v & 0xFFFF0000u); }

// ---------------- init: zero histogram counters + BN stat shards + pool accumulator ----------------
__global__ void k_init(int* __restrict__ cnt, float* __restrict__ stats,
                       float* __restrict__ gbuf) {
    int i = blockIdx.x * blockDim.x + threadIdx.x;
    if (i < NNODES) cnt[i] = 0;
    if (i < NGRAPH * CH) gbuf[i] = 0.f;   // NGRAPH*CH == NNODES
    if (i < NSHARD * SHSTRIDE) stats[i] = 0.f;
}

// ---------------- in-degree histogram over dst ----------------
__global__ void k_hist(const int* __restrict__ dst, int* __restrict__ cnt) {
    int e = blockIdx.x * blockDim.x + threadIdx.x;
    if (e < NEDGES) atomicAdd(&cnt[dst[e]], 1);
}

// ---------------- pack x (50000 x 33 fp32) into bf16 rows of 17 uints ----------------
__global__ void k_packx(const float* __restrict__ x, unsigned* __restrict__ xb) {
    int i = blockIdx.x * blockDim.x + threadIdx.x;
    if (i >= NNODES * 17) return;
    int r = i / 17, s = i % 17;
    float a = x[r * CIN0 + 2 * s];
    float b = (2 * s + 1 < CIN0) ? x[r * CIN0 + 2 * s + 1] : 0.f;
    xb[i] = pack_bf16(a, b);
}

// ---------------- exclusive scan of cnt -> rowptr; also dinv = rsqrt(cnt+1) ----------------
__global__ void k_scan1(const int* __restrict__ cnt, int* __restrict__ rowptr,
                        int* __restrict__ blkSums, float* __restrict__ dinv) {
    __shared__ int ts[SCAN_TPB];
    int tid = threadIdx.x;
    int base = blockIdx.x * SCAN_TILE + tid * SCAN_IPT;
    int v[SCAN_IPT];
    int s = 0;
    #pragma unroll
    for (int j = 0; j < SCAN_IPT; ++j) {
        int i = base + j;
        v[j] = (i < NNODES) ? cnt[i] : 0;
        if (i < NNODES) dinv[i] = rsqrtf((float)(v[j] + 1));
        s += v[j];
    }
    ts[tid] = s;
    __syncthreads();
    for (int off = 1; off < SCAN_TPB; off <<= 1) {
        int add = (tid >= off) ? ts[tid - off] : 0;
        __syncthreads();
        ts[tid] += add;
        __syncthreads();
    }
    int run = ts[tid] - s;  // exclusive prefix within block
    #pragma unroll
    for (int j = 0; j < SCAN_IPT; ++j) {
        int i = base + j;
        if (i < NNODES) rowptr[i] = run;
        run += v[j];
    }
    if (tid == SCAN_TPB - 1) blkSums[blockIdx.x] = ts[tid];
}

__global__ void k_scan2(const int* __restrict__ blkSums, int* __restrict__ blkOff) {
    if (threadIdx.x == 0) {
        int run = 0;
        for (int i = 0; i < SCAN_BLOCKS; ++i) { blkOff[i] = run; run += blkSums[i]; }
    }
}

__global__ void k_scan3(int* __restrict__ rowptr, int* __restrict__ cursor,
                        const int* __restrict__ blkOff) {
    int off = blkOff[blockIdx.x];
    int base = blockIdx.x * SCAN_TILE + threadIdx.x * SCAN_IPT;
    #pragma unroll
    for (int j = 0; j < SCAN_IPT; ++j) {
        int i = base + j;
        if (i < NNODES) {
            int vv = rowptr[i] + off;
            rowptr[i] = vv;
            cursor[i] = vv;
        }
    }
    if (blockIdx.x == 0 && threadIdx.x == 0) rowptr[NNODES] = NEDGES;
}

// ---------------- scatter edges into CSR (by dst); pack (src, dinv[src]) ----------------
__global__ void k_scatter(const int* __restrict__ src, const int* __restrict__ dst,
                          const float* __restrict__ dinv, int* __restrict__ cursor,
                          int2* __restrict__ ew) {
    int e = blockIdx.x * blockDim.x + threadIdx.x;
    if (e < NEDGES) {
        int d = dst[e], s = src[e];
        int pos = atomicAdd(&cursor[d], 1);
        ew[pos] = make_int2(s, __float_as_int(dinv[s]));
    }
}

// ---------------- aggregate over bf16-packed rows, fused BN(+ReLU) ----------------
// Input rows: CPACK uints (bf16 pairs). Lane l < CPACK owns channels (2l, 2l+1).
// a[i] = dinv[i]*( sum_e dinv[src]*f(h[src]) + dinv[i]*f(h[i]) ).
// OBF=false: output fp32, row stride OS floats (pad zero-filled).
// OBF=true:  output bf16-packed, row stride OS uints.
template<int CPACK, int OS, bool BN, bool OBF>
__global__ __launch_bounds__(256) void k_aggregate_bf16(
    const unsigned* __restrict__ h, void* __restrict__ aout, const int* __restrict__ rowptr,
    const int2* __restrict__ ew, const float* __restrict__ dinv,
    const float* __restrict__ gsum, const float* __restrict__ gsq,
    const float* __restrict__ gamma, const float* __restrict__ beta) {
    int node = (blockIdx.x * 256 + threadIdx.x) >> 6;
    int lane = threadIdx.x & 63;
    if (node >= NNODES) return;
    int p0 = rowptr[node], p1 = rowptr[node + 1];
    float di = dinv[node];
    constexpr float invN = 1.f / NNODES;
    bool act = lane < CPACK;

    float scx = 0.f, scy = 0.f, shx = 0.f, shy = 0.f;
    if (BN && act) {
        float sx = 0.f, sy = 0.f, qx = 0.f, qy = 0.f;
        #pragma unroll
        for (int sh = 0; sh < NSHARD; ++sh) {
            float2 s2 = ((const float2*)(gsum + sh * SHSTRIDE))[lane];
            float2 q2 = ((const float2*)(gsq + sh * SHSTRIDE))[lane];
            sx += s2.x; sy += s2.y; qx += q2.x; qy += q2.y;
        }
        float2 g2 = ((const float2*)gamma)[lane];
        float2 b2 = ((const float2*)beta)[lane];
        float mx = sx * invN, my = sy * invN;
        float vx = qx * invN - mx * mx, vy = qy * invN - my * my;
        scx = g2.x * rsqrtf(vx + BN_EPS); shx = b2.x - mx * scx;
        scy = g2.y * rsqrtf(vy + BN_EPS); shy = b2.y - my * scy;
    }
    unsigned hvp = 0;
    if (act) hvp = h[(size_t)node * CPACK + lane];

    float ax = 0.f, ay = 0.f;
    for (int base = p0; base < p1; base += 64) {
        int nn = p1 - base; if (nn > 64) nn = 64;
        int2 e = make_int2(0, 0);
        if (lane < nn) e = ew[base + lane];
        int myc = e.x; float myw = __int_as_float(e.y);
        int j = 0;
        for (; j + 16 <= nn; j += 16) {
            int s[16]; float w[16];
            #pragma unroll
            for (int t = 0; t < 16; ++t) { s[t] = __shfl(myc, j + t); w[t] = __shfl(myw, j + t); }
            if (act) {
                unsigned v[16];
                #pragma unroll
                for (int t = 0; t < 16; ++t) v[t] = h[(size_t)s[t] * CPACK + lane];
                #pragma unroll
                for (int t = 0; t < 16; ++t) {
                    float vx = unp_lo(v[t]), vy = unp_hi(v[t]);
                    if (BN) {
                        vx = fmaxf(vx * scx + shx, 0.f);
                        vy = fmaxf(vy * scy + shy, 0.f);
                    }
                    ax += w[t] * vx; ay += w[t] * vy;
                }
            }
        }
        for (; j + 4 <= nn; j += 4) {
            int s[4]; float w[4];
            #pragma unroll
            for (int t = 0; t < 4; ++t) { s[t] = __shfl(myc, j + t); w[t] = __shfl(myw, j + t); }
            if (act) {
                unsigned v[4];
                #pragma unroll
                for (int t = 0; t < 4; ++t) v[t] = h[(size_t)s[t] * CPACK + lane];
                #pragma unroll
                for (int t = 0; t < 4; ++t) {
                    float vx = unp_lo(v[t]), vy = unp_hi(v[t]);
                    if (BN) {
                        vx = fmaxf(vx * scx + shx, 0.f);
                        vy = fmaxf(vy * scy + shy, 0.f);
                    }
                    ax += w[t] * vx; ay += w[t] * vy;
                }
            }
        }
        for (; j < nn; ++j) {
            int s0 = __shfl(myc, j);
            float w0 = __shfl(myw, j);
            if (act) {
                unsigned v = h[(size_t)s0 * CPACK + lane];
                float vx = unp_lo(v), vy = unp_hi(v);
                if (BN) {
                    vx = fmaxf(vx * scx + shx, 0.f);
                    vy = fmaxf(vy * scy + shy, 0.f);
                }
                ax += w0 * vx; ay += w0 * vy;
            }
        }
    }
    float ox = 0.f, oy = 0.f;
    if (act) {
        float hx = unp_lo(hvp), hy = unp_hi(hvp);
        if (BN) {
            hx = fmaxf(hx * scx + shx, 0.f);
            hy = fmaxf(hy * scy + shy, 0.f);
        }
        ox = di * (ax + di * hx);
        oy = di * (ay + di * hy);
    }
    if constexpr (OBF) {
        if (lane < OS)
            ((unsigned*)aout)[(size_t)node * OS + lane] = pack_bf16(ox, oy);
    } else {
        if (lane < (OS + 1) / 2)
            ((float2*)((float*)aout + (size_t)node * OS))[lane] = make_float2(ox, oy);
    }
}

// ---------------- CH-layer GEMM (512 thr, 4x4 tile; R14 hot loop) ----------------
// A arrives bf16-packed (50 uints/row) and is unpacked to fp32 DURING LDS staging
// (one unpack per element, hot loop untouched). W fp32 staged flat (R14 path).
// LDS = 40 KB (W) + 25.6 KB (A) + 0.8 KB = 66.4 KB -> 2 blocks/CU (R14 config).
__global__ __launch_bounds__(512) void k_gemm_ch(
    const unsigned* __restrict__ Ab, const float* __restrict__ W,
    const float* __restrict__ bias, unsigned* __restrict__ Zb,
    float* __restrict__ gsum, float* __restrict__ gsq) {
    __shared__ __align__(16) float wS[CH * CH];   // 40 KB
    __shared__ __align__(16) float aS[64 * CH];   // 25.6 KB
    __shared__ float sSum[CH], sSq[CH];
    int tid = threadIdx.x;
    for (int i = tid; i < CH; i += 512) { sSum[i] = 0.f; sSq[i] = 0.f; }
    for (int i = tid; i < CH * CH; i += 512) wS[i] = W[i];
    int row0 = blockIdx.x * 64;
    {
        const unsigned* As = Ab + (size_t)row0 * 50;
        int maxI = (NNODES - row0) * 50;   // >= 3200 except last block
        for (int i = tid; i < 64 * 50; i += 512) {
            unsigned v = (i < maxI) ? As[i] : 0u;
            ((float2*)aS)[i] = make_float2(unp_lo(v), unp_hi(v));
        }
    }
    __syncthreads();
    if (tid < 400) {
        int ct = tid % 25, rt = tid / 25;  // ct 0..24, rt 0..15
        int c0 = ct * 4, r0 = rt * 4;
        float acc[4][4] = {};
        for (int k = 0; k < CH; k += 4) {
            float4 w0 = *(const float4*)&wS[(k + 0) * CH + c0];
            float4 w1 = *(const float4*)&wS[(k + 1) * CH + c0];
            float4 w2 = *(const float4*)&wS[(k + 2) * CH + c0];
            float4 w3 = *(const float4*)&wS[(k + 3) * CH + c0];
            #pragma unroll
            for (int j = 0; j < 4; ++j) {
                float4 av = *(const float4*)&aS[(r0 + j) * CH + k];
                acc[j][0] += av.x * w0.x + av.y * w1.x + av.z * w2.x + av.w * w3.x;
                acc[j][1] += av.x * w0.y + av.y * w1.y + av.z * w2.y + av.w * w3.y;
                acc[j][2] += av.x * w0.z + av.y * w1.z + av.z * w2.z + av.w * w3.z;
                acc[j][3] += av.x * w0.w + av.y * w1.w + av.z * w2.w + av.w * w3.w;
            }
        }
        float4 bv = *(const float4*)&bias[c0];
        float cs0 = 0, cs1 = 0, cs2 = 0, cs3 = 0, cq0 = 0, cq1 = 0, cq2 = 0, cq3 = 0;
        #pragma unroll
        for (int j = 0; j < 4; ++j) {
            int r = row0 + r0 + j;
            if (r < NNODES) {
                float z0 = acc[j][0] + bv.x, z1 = acc[j][1] + bv.y;
                float z2 = acc[j][2] + bv.z, z3 = acc[j][3] + bv.w;
                *(uint2*)&Zb[(size_t)r * 50 + (c0 >> 1)] =
                    make_uint2(pack_bf16(z0, z1), pack_bf16(z2, z3));
                cs0 += z0; cs1 += z1; cs2 += z2; cs3 += z3;
                cq0 += z0 * z0; cq1 += z1 * z1; cq2 += z2 * z2; cq3 += z3 * z3;
            }
        }
        atomicAdd(&sSum[c0], cs0); atomicAdd(&sSum[c0 + 1], cs1);
        atomicAdd(&sSum[c0 + 2], cs2); atomicAdd(&sSum[c0 + 3], cs3);
        atomicAdd(&sSq[c0], cq0); atomicAdd(&sSq[c0 + 1], cq1);
        atomicAdd(&sSq[c0 + 2], cq2); atomicAdd(&sSq[c0 + 3], cq3);
    }
    __syncthreads();
    int sh = (blockIdx.x & (NSHARD - 1)) * SHSTRIDE;
    if (tid < CH) { atomicAdd(&gsum[sh + tid], sSum[tid]); atomicAdd(&gsq[sh + tid], sSq[tid]); }
}

// ---------------- layer-0 GEMM (256 thr, 64-row tile, fp32) -> bf16 Z + sharded stats ----------------
// Two sequential 4-row passes (unroll 1) keep only one 4x4 acc set live -> low VGPR.
__global__ __launch_bounds__(256) void k_gemm0(
    const float* __restrict__ A, const float* __restrict__ W, const float* __restrict__ bias,
    unsigned* __restrict__ Zb, float* __restrict__ gsum, float* __restrict__ gsq) {
    constexpr int K = CIN0, KP = 36;
    __shared__ __align__(16) float wS[KP * CH];
    __shared__ __align__(16) float aS[64 * KP];
    __shared__ float sSum[CH], sSq[CH];
    int tid = threadIdx.x;
    for (int i = tid; i < CH; i += 256) { sSum[i] = 0.f; sSq[i] = 0.f; }
    for (int i = tid; i < KP * CH; i += 256) wS[i] = (i < K * CH) ? W[i] : 0.f;
    int row0 = blockIdx.x * 64;
    {
        const float* Ab = A + (size_t)row0 * KP;
        int maxI = (NNODES - row0) * KP;
        for (int i = tid; i < 64 * KP; i += 256) aS[i] = (i < maxI) ? Ab[i] : 0.f;
    }
    __syncthreads();
    if (tid < 200) {
        int ct = tid % 25, rt = tid / 25;  // ct 0..24, rt 0..7
        int c0 = ct * 4;
        float4 bv = *(const float4*)&bias[c0];
        float cs0 = 0, cs1 = 0, cs2 = 0, cs3 = 0, cq0 = 0, cq1 = 0, cq2 = 0, cq3 = 0;
        #pragma unroll 1
        for (int half = 0; half < 2; ++half) {
            int r0 = rt * 8 + half * 4;
            float acc[4][4] = {};
            #pragma unroll
            for (int k = 0; k < KP; k += 4) {
                float4 w0 = *(const float4*)&wS[(k + 0) * CH + c0];
                float4 w1 = *(const float4*)&wS[(k + 1) * CH + c0];
                float4 w2 = *(const float4*)&wS[(k + 2) * CH + c0];
                float4 w3 = *(const float4*)&wS[(k + 3) * CH + c0];
                #pragma unroll
                for (int j = 0; j < 4; ++j) {
                    float4 av = *(const float4*)&aS[(r0 + j) * KP + k];
                    acc[j][0] += av.x * w0.x + av.y * w1.x + av.z * w2.x + av.w * w3.x;
                    acc[j][1] += av.x * w0.y + av.y * w1.y + av.z * w2.y + av.w * w3.y;
                    acc[j][2] += av.x * w0.z + av.y * w1.z + av.z * w2.z + av.w * w3.z;
                    acc[j][3] += av.x * w0.w + av.y * w1.w + av.z * w2.w + av.w * w3.w;
                }
            }
            #pragma unroll
            for (int j = 0; j < 4; ++j) {
                int r = row0 + r0 + j;
                if (r < NNODES) {
                    float z0 = acc[j][0] + bv.x, z1 = acc[j][1] + bv.y;
                    float z2 = acc[j][2] + bv.z, z3 = acc[j][3] + bv.w;
                    *(uint2*)&Zb[(size_t)r * 50 + (c0 >> 1)] =
                        make_uint2(pack_bf16(z0, z1), pack_bf16(z2, z3));
                    cs0 += z0; cs1 += z1; cs2 += z2; cs3 += z3;
                    cq0 += z0 * z0; cq1 += z1 * z1; cq2 += z2 * z2; cq3 += z3 * z3;
                }
            }
        }
        atomicAdd(&sSum[c0], cs0); atomicAdd(&sSum[c0 + 1], cs1);
        atomicAdd(&sSum[c0 + 2], cs2); atomicAdd(&sSum[c0 + 3], cs3);
        atomicAdd(&sSq[c0], cq0); atomicAdd(&sSq[c0 + 1], cq1);
        atomicAdd(&sSq[c0 + 2], cq2); atomicAdd(&sSq[c0 + 3], cq3);
    }
    __syncthreads();
    int sh = (blockIdx.x & (NSHARD - 1)) * SHSTRIDE;
    if (tid < CH) { atomicAdd(&gsum[sh + tid], sSum[tid]); atomicAdd(&gsq[sh + tid], sSq[tid]); }
}

// ---------------- global_add_pool of BN(z) from bf16 Z; 4 row-chunks per graph ----------------
__global__ void k_pool(const unsigned* __restrict__ Zl, const int* __restrict__ batch,
                       const float* __restrict__ gsum, const float* __restrict__ gsq,
                       const float* __restrict__ gamma, const float* __restrict__ beta,
                       float* __restrict__ g) {
    int gid = blockIdx.x;
    int part = blockIdx.y;
    int lo = 0, hi = NNODES;
    while (lo < hi) { int mid = (lo + hi) >> 1; if (batch[mid] < gid) lo = mid + 1; else hi = mid; }
    int start = lo;
    hi = NNODES;
    while (lo < hi) { int mid = (lo + hi) >> 1; if (batch[mid] < gid + 1) lo = mid + 1; else hi = mid; }
    int end = lo;
    int len = end - start;
    int cb = (len + 3) >> 2;
    int s = start + part * cb;
    int e = s + cb; if (e > end) e = end;
    if (s >= e) return;
    int t = threadIdx.x;
    if (t >= 50) return;
    float su = 0.f, sv = 0.f, qu = 0.f, qv = 0.f;
    #pragma unroll
    for (int sh = 0; sh < NSHARD; ++sh) {
        float2 s2 = ((const float2*)(gsum + sh * SHSTRIDE))[t];
        float2 q2 = ((const float2*)(gsq + sh * SHSTRIDE))[t];
        su += s2.x; sv += s2.y; qu += q2.x; qv += q2.y;
    }
    constexpr float invN = 1.f / NNODES;
    float2 g2 = ((const float2*)gamma)[t];
    float2 b2 = ((const float2*)beta)[t];
    float mx = su * invN, my = sv * invN;
    float vx = qu * invN - mx * mx, vy = qv * invN - my * my;
    float scx = g2.x * rsqrtf(vx + BN_EPS), shx = b2.x - mx * scx;
    float scy = g2.y * rsqrtf(vy + BN_EPS), shy = b2.y - my * scy;
    float sx = 0.f, sy = 0.f;
    for (int r = s; r < e; ++r) {
        unsigned v = Zl[(size_t)r * 50 + t];
        sx += unp_lo(v); sy += unp_hi(v);
    }
    float n = (float)(e - s);
    atomicAdd(&g[gid * CH + 2 * t], sx * scx + n * shx);
    atomicAdd(&g[gid * CH + 2 * t + 1], sy * scy + n * shy);
}

// ---------------- out = leakyrelu(g @ Wout + bout, 0.1) ----------------
__global__ __launch_bounds__(256) void k_out(const float* __restrict__ g,
                                             const float* __restrict__ Wout,
                                             const float* __restrict__ bout,
                                             float* __restrict__ out) {
    __shared__ float gS[CH];
    int gid = blockIdx.x, tid = threadIdx.x;
    if (tid < CH) gS[tid] = g[gid * CH + tid];
    __syncthreads();
    if (tid >= 200) return;
    float acc = bout[tid];
    for (int k = 0; k < CH; ++k) acc += gS[k] * Wout[k * 200 + tid];
    out[gid * 200 + tid] = acc > 0.f ? acc : 0.1f * acc;
}

extern "C" void kernel_launch(void* const* d_in, const int* in_sizes, int n_in,
                              void* d_out, int out_size, void* d_ws, size_t ws_size,
                              hipStream_t stream) {
    const float* x = (const float*)d_in[0];
    const int* ei = (const int*)d_in[1];
    const int* batch = (const int*)d_in[2];
    const float* W0 = (const float*)d_in[3];
    const float* Wrest = (const float*)d_in[4];
    const float* b = (const float*)d_in[5];
    const float* gamma = (const float*)d_in[6];
    const float* beta = (const float*)d_in[7];
    const float* Wout = (const float*)d_in[8];
    const float* bout = (const float*)d_in[9];
    float* out = (float*)d_out;
    const int* srcA = ei;
    const int* dstA = ei + NEDGES;

    char* wsb = (char*)d_ws;
    size_t off = 0;
    auto alloc = [&](size_t elems) -> void* {
        void* p = (void*)(wsb + off);
        off += ((elems + 7) & ~(size_t)7) * 4;
        return p;
    };
    int* cnt = (int*)alloc(NNODES);
    int* rowptr = (int*)alloc(NNODES + 1);
    int* cursor = (int*)alloc(NNODES);
    float* dinv = (float*)alloc(NNODES);
    int* scanBlk = (int*)alloc(64);
    int* scanOff = (int*)alloc(64);
    float* stats = (float*)alloc(NSHARD * SHSTRIDE);  // per shard: [l*128]=sum, [512+l*128]=sq
    int2* ew = (int2*)alloc(2 * (size_t)NEDGES);
    unsigned* xb = (unsigned*)alloc((size_t)NNODES * 17);
    float* A0 = (float*)alloc((size_t)NNODES * 36);
    unsigned* Abf = (unsigned*)alloc((size_t)NNODES * 50);
    unsigned* Zb = (unsigned*)alloc((size_t)NNODES * 50);
    float* gbuf = (float*)alloc((size_t)NGRAPH * CH);
    (void)ws_size; (void)n_in; (void)in_sizes; (void)out_size;

    hipLaunchKernelGGL(k_init, dim3((NNODES + 255) / 256), dim3(256), 0, stream, cnt, stats, gbuf);
    hipLaunchKernelGGL(k_hist, dim3((NEDGES + 255) / 256), dim3(256), 0, stream, dstA, cnt);
    hipLaunchKernelGGL(k_packx, dim3((NNODES * 17 + 255) / 256), dim3(256), 0, stream, x, xb);
    hipLaunchKernelGGL(k_scan1, dim3(SCAN_BLOCKS), dim3(SCAN_TPB), 0, stream, cnt, rowptr, scanBlk, dinv);
    hipLaunchKernelGGL(k_scan2, dim3(1), dim3(64), 0, stream, scanBlk, scanOff);
    hipLaunchKernelGGL(k_scan3, dim3(SCAN_BLOCKS), dim3(SCAN_TPB), 0, stream, rowptr, cursor, scanOff);
    hipLaunchKernelGGL(k_scatter, dim3((NEDGES + 255) / 256), dim3(256), 0, stream,
                       srcA, dstA, dinv, cursor, ew);

    for (int l = 0; l < 4; ++l) {
        float* gs = stats + l * 128;          // + shard*SHSTRIDE inside kernels
        float* gq = stats + 512 + l * 128;
        if (l == 0) {
            hipLaunchKernelGGL((k_aggregate_bf16<17, 36, false, false>), dim3(12500), dim3(256), 0,
                               stream, xb, A0, rowptr, ew, dinv,
                               (const float*)nullptr, (const float*)nullptr,
                               (const float*)nullptr, (const float*)nullptr);
            hipLaunchKernelGGL(k_gemm0, dim3((NNODES + 63) / 64), dim3(256), 0, stream,
                               A0, W0, b, Zb, gs, gq);
        } else {
            float* ps = stats + (l - 1) * 128;
            float* pq = stats + 512 + (l - 1) * 128;
            hipLaunchKernelGGL((k_aggregate_bf16<50, 50, true, true>), dim3(12500), dim3(256), 0,
                               stream, Zb, Abf, rowptr, ew, dinv,
                               ps, pq, gamma + (l - 1) * CH, beta + (l - 1) * CH);
            hipLaunchKernelGGL(k_gemm_ch, dim3((NNODES + 63) / 64), dim3(512), 0, stream,
                               Abf, Wrest + (l - 1) * 10000, b + l * CH, Zb, gs, gq);
        }
    }
    hipLaunchKernelGGL(k_pool, dim3(NGRAPH, 4), dim3(64), 0, stream, Zb, batch,
                       stats + 3 * 128, stats + 512 + 3 * 128, gamma + 3 * CH, beta + 3 * CH, gbuf);
    hipLaunchKernelGGL(k_out, dim3(NGRAPH), dim3(256), 0, stream, gbuf, Wout, bout, out);
}

// Round 19
// 530.798 us; speedup vs baseline: 2.1135x; 1.0199x over previous
//
#include <hip/hip_runtime.h>

#define NNODES 50000
#define NEDGES 800000
#define NGRAPH 500
#define CH 100
#define CIN0 33
#define BN_EPS 1e-5f
#define NSHARD 8
#define SHSTRIDE 1024   // floats per shard: [4 layers][sum128|sq128]

#define SCAN_TPB 256
#define SCAN_IPT 4
#define SCAN_TILE (SCAN_TPB * SCAN_IPT)
#define SCAN_BLOCKS ((NNODES + SCAN_TILE - 1) / SCAN_TILE)

// pack two fp32 into (bf16(x) | bf16(y)<<16), round-to-nearest-even
__device__ inline unsigned pack_bf16(float x, float y) {
    unsigned xb = __float_as_uint(x);
    unsigned yb = __float_as_uint(y);
    xb += 0x7FFF + ((xb >> 16) & 1);
    yb += 0x7FFF + ((yb >> 16) & 1);
    return (xb >> 16) | (yb & 0xFFFF0000u);
}
__device__ inline float unp_lo(unsigned v) { return __uint_as_float(v << 16); }
__device__ inline float unp_hi(unsigned v) { return __uint_as_float(v & 0xFFFF0000u); }

// ---------------- init: zero histogram counters + BN stat shards + pool accumulator ----------------
__global__ void k_init(int* __restrict__ cnt, float* __restrict__ stats,
                       float* __restrict__ gbuf) {
    int i = blockIdx.x * blockDim.x + threadIdx.x;
    if (i < NNODES) cnt[i] = 0;
    if (i < NGRAPH * CH) gbuf[i] = 0.f;   // NGRAPH*CH == NNODES
    if (i < NSHARD * SHSTRIDE) stats[i] = 0.f;
}

// ---------------- in-degree histogram over dst ----------------
__global__ void k_hist(const int* __restrict__ dst, int* __restrict__ cnt) {
    int e = blockIdx.x * blockDim.x + threadIdx.x;
    if (e < NEDGES) atomicAdd(&cnt[dst[e]], 1);
}

// ---------------- pack x (50000 x 33 fp32) into bf16 rows of 17 uints ----------------
__global__ void k_packx(const float* __restrict__ x, unsigned* __restrict__ xb) {
    int i = blockIdx.x * blockDim.x + threadIdx.x;
    if (i >= NNODES * 17) return;
    int r = i / 17, s = i % 17;
    float a = x[r * CIN0 + 2 * s];
    float b = (2 * s + 1 < CIN0) ? x[r * CIN0 + 2 * s + 1] : 0.f;
    xb[i] = pack_bf16(a, b);
}

// ---------------- exclusive scan of cnt -> rowptr; also dinv = rsqrt(cnt+1) ----------------
__global__ void k_scan1(const int* __restrict__ cnt, int* __restrict__ rowptr,
                        int* __restrict__ blkSums, float* __restrict__ dinv) {
    __shared__ int ts[SCAN_TPB];
    int tid = threadIdx.x;
    int base = blockIdx.x * SCAN_TILE + tid * SCAN_IPT;
    int v[SCAN_IPT];
    int s = 0;
    #pragma unroll
    for (int j = 0; j < SCAN_IPT; ++j) {
        int i = base + j;
        v[j] = (i < NNODES) ? cnt[i] : 0;
        if (i < NNODES) dinv[i] = rsqrtf((float)(v[j] + 1));
        s += v[j];
    }
    ts[tid] = s;
    __syncthreads();
    for (int off = 1; off < SCAN_TPB; off <<= 1) {
        int add = (tid >= off) ? ts[tid - off] : 0;
        __syncthreads();
        ts[tid] += add;
        __syncthreads();
    }
    int run = ts[tid] - s;  // exclusive prefix within block
    #pragma unroll
    for (int j = 0; j < SCAN_IPT; ++j) {
        int i = base + j;
        if (i < NNODES) rowptr[i] = run;
        run += v[j];
    }
    if (tid == SCAN_TPB - 1) blkSums[blockIdx.x] = ts[tid];
}

__global__ void k_scan2(const int* __restrict__ blkSums, int* __restrict__ blkOff) {
    if (threadIdx.x == 0) {
        int run = 0;
        for (int i = 0; i < SCAN_BLOCKS; ++i) { blkOff[i] = run; run += blkSums[i]; }
    }
}

__global__ void k_scan3(int* __restrict__ rowptr, int* __restrict__ cursor,
                        const int* __restrict__ blkOff) {
    int off = blkOff[blockIdx.x];
    int base = blockIdx.x * SCAN_TILE + threadIdx.x * SCAN_IPT;
    #pragma unroll
    for (int j = 0; j < SCAN_IPT; ++j) {
        int i = base + j;
        if (i < NNODES) {
            int vv = rowptr[i] + off;
            rowptr[i] = vv;
            cursor[i] = vv;
        }
    }
    if (blockIdx.x == 0 && threadIdx.x == 0) rowptr[NNODES] = NEDGES;
}

// ---------------- scatter edges into CSR (by dst); pack (src, dinv[src]) ----------------
__global__ void k_scatter(const int* __restrict__ src, const int* __restrict__ dst,
                          const float* __restrict__ dinv, int* __restrict__ cursor,
                          int2* __restrict__ ew) {
    int e = blockIdx.x * blockDim.x + threadIdx.x;
    if (e < NEDGES) {
        int d = dst[e], s = src[e];
        int pos = atomicAdd(&cursor[d], 1);
        ew[pos] = make_int2(s, __float_as_int(dinv[s]));
    }
}

// ---------------- aggregate over bf16-packed rows, fused BN(+ReLU) ----------------
// Input rows: CPACK uints (bf16 pairs). Lane l < CPACK owns channels (2l, 2l+1).
// a[i] = dinv[i]*( sum_e dinv[src]*f(h[src]) + dinv[i]*f(h[i]) ).
// OBF=false: output fp32, row stride OS floats (pad zero-filled).
// OBF=true:  output bf16-packed, row stride OS uints.
template<int CPACK, int OS, bool BN, bool OBF>
__global__ __launch_bounds__(256) void k_aggregate_bf16(
    const unsigned* __restrict__ h, void* __restrict__ aout, const int* __restrict__ rowptr,
    const int2* __restrict__ ew, const float* __restrict__ dinv,
    const float* __restrict__ gsum, const float* __restrict__ gsq,
    const float* __restrict__ gamma, const float* __restrict__ beta) {
    int node = (blockIdx.x * 256 + threadIdx.x) >> 6;
    int lane = threadIdx.x & 63;
    if (node >= NNODES) return;
    int p0 = rowptr[node], p1 = rowptr[node + 1];
    float di = dinv[node];
    constexpr float invN = 1.f / NNODES;
    bool act = lane < CPACK;

    float scx = 0.f, scy = 0.f, shx = 0.f, shy = 0.f;
    if (BN && act) {
        float sx = 0.f, sy = 0.f, qx = 0.f, qy = 0.f;
        #pragma unroll
        for (int sh = 0; sh < NSHARD; ++sh) {
            float2 s2 = ((const float2*)(gsum + sh * SHSTRIDE))[lane];
            float2 q2 = ((const float2*)(gsq + sh * SHSTRIDE))[lane];
            sx += s2.x; sy += s2.y; qx += q2.x; qy += q2.y;
        }
        float2 g2 = ((const float2*)gamma)[lane];
        float2 b2 = ((const float2*)beta)[lane];
        float mx = sx * invN, my = sy * invN;
        float vx = qx * invN - mx * mx, vy = qy * invN - my * my;
        scx = g2.x * rsqrtf(vx + BN_EPS); shx = b2.x - mx * scx;
        scy = g2.y * rsqrtf(vy + BN_EPS); shy = b2.y - my * scy;
    }
    unsigned hvp = 0;
    if (act) hvp = h[(size_t)node * CPACK + lane];

    float ax = 0.f, ay = 0.f;
    for (int base = p0; base < p1; base += 64) {
        int nn = p1 - base; if (nn > 64) nn = 64;
        int2 e = make_int2(0, 0);
        if (lane < nn) e = ew[base + lane];
        int myc = e.x; float myw = __int_as_float(e.y);
        int j = 0;
        for (; j + 16 <= nn; j += 16) {
            int s[16]; float w[16];
            #pragma unroll
            for (int t = 0; t < 16; ++t) { s[t] = __shfl(myc, j + t); w[t] = __shfl(myw, j + t); }
            if (act) {
                unsigned v[16];
                #pragma unroll
                for (int t = 0; t < 16; ++t) v[t] = h[(size_t)s[t] * CPACK + lane];
                #pragma unroll
                for (int t = 0; t < 16; ++t) {
                    float vx = unp_lo(v[t]), vy = unp_hi(v[t]);
                    if (BN) {
                        vx = fmaxf(vx * scx + shx, 0.f);
                        vy = fmaxf(vy * scy + shy, 0.f);
                    }
                    ax += w[t] * vx; ay += w[t] * vy;
                }
            }
        }
        for (; j + 4 <= nn; j += 4) {
            int s[4]; float w[4];
            #pragma unroll
            for (int t = 0; t < 4; ++t) { s[t] = __shfl(myc, j + t); w[t] = __shfl(myw, j + t); }
            if (act) {
                unsigned v[4];
                #pragma unroll
                for (int t = 0; t < 4; ++t) v[t] = h[(size_t)s[t] * CPACK + lane];
                #pragma unroll
                for (int t = 0; t < 4; ++t) {
                    float vx = unp_lo(v[t]), vy = unp_hi(v[t]);
                    if (BN) {
                        vx = fmaxf(vx * scx + shx, 0.f);
                        vy = fmaxf(vy * scy + shy, 0.f);
                    }
                    ax += w[t] * vx; ay += w[t] * vy;
                }
            }
        }
        for (; j < nn; ++j) {
            int s0 = __shfl(myc, j);
            float w0 = __shfl(myw, j);
            if (act) {
                unsigned v = h[(size_t)s0 * CPACK + lane];
                float vx = unp_lo(v), vy = unp_hi(v);
                if (BN) {
                    vx = fmaxf(vx * scx + shx, 0.f);
                    vy = fmaxf(vy * scy + shy, 0.f);
                }
                ax += w0 * vx; ay += w0 * vy;
            }
        }
    }
    float ox = 0.f, oy = 0.f;
    if (act) {
        float hx = unp_lo(hvp), hy = unp_hi(hvp);
        if (BN) {
            hx = fmaxf(hx * scx + shx, 0.f);
            hy = fmaxf(hy * scy + shy, 0.f);
        }
        ox = di * (ax + di * hx);
        oy = di * (ay + di * hy);
    }
    if constexpr (OBF) {
        if (lane < OS)
            ((unsigned*)aout)[(size_t)node * OS + lane] = pack_bf16(ox, oy);
    } else {
        if (lane < (OS + 1) / 2)
            ((float2*)((float*)aout + (size_t)node * OS))[lane] = make_float2(ox, oy);
    }
}

// ---------------- CH-layer GEMM (512 thr, 4x4 tile; R14 hot loop) ----------------
// A arrives bf16-packed (50 uints/row) and is unpacked to fp32 DURING LDS staging
// (one unpack per element, hot loop untouched). W fp32 staged flat (R14 path).
// LDS = 40 KB (W) + 25.6 KB (A) + 0.8 KB = 66.4 KB -> 2 blocks/CU (R14 config).
__global__ __launch_bounds__(512) void k_gemm_ch(
    const unsigned* __restrict__ Ab, const float* __restrict__ W,
    const float* __restrict__ bias, unsigned* __restrict__ Zb,
    float* __restrict__ gsum, float* __restrict__ gsq) {
    __shared__ __align__(16) float wS[CH * CH];   // 40 KB
    __shared__ __align__(16) float aS[64 * CH];   // 25.6 KB
    __shared__ float sSum[CH], sSq[CH];
    int tid = threadIdx.x;
    for (int i = tid; i < CH; i += 512) { sSum[i] = 0.f; sSq[i] = 0.f; }
    for (int i = tid; i < CH * CH; i += 512) wS[i] = W[i];
    int row0 = blockIdx.x * 64;
    {
        const unsigned* As = Ab + (size_t)row0 * 50;
        int maxI = (NNODES - row0) * 50;   // >= 3200 except last block
        for (int i = tid; i < 64 * 50; i += 512) {
            unsigned v = (i < maxI) ? As[i] : 0u;
            ((float2*)aS)[i] = make_float2(unp_lo(v), unp_hi(v));
        }
    }
    __syncthreads();
    if (tid < 400) {
        int ct = tid % 25, rt = tid / 25;  // ct 0..24, rt 0..15
        int c0 = ct * 4, r0 = rt * 4;
        float acc[4][4] = {};
        for (int k = 0; k < CH; k += 4) {
            float4 w0 = *(const float4*)&wS[(k + 0) * CH + c0];
            float4 w1 = *(const float4*)&wS[(k + 1) * CH + c0];
            float4 w2 = *(const float4*)&wS[(k + 2) * CH + c0];
            float4 w3 = *(const float4*)&wS[(k + 3) * CH + c0];
            #pragma unroll
            for (int j = 0; j < 4; ++j) {
                float4 av = *(const float4*)&aS[(r0 + j) * CH + k];
                acc[j][0] += av.x * w0.x + av.y * w1.x + av.z * w2.x + av.w * w3.x;
                acc[j][1] += av.x * w0.y + av.y * w1.y + av.z * w2.y + av.w * w3.y;
                acc[j][2] += av.x * w0.z + av.y * w1.z + av.z * w2.z + av.w * w3.z;
                acc[j][3] += av.x * w0.w + av.y * w1.w + av.z * w2.w + av.w * w3.w;
            }
        }
        float4 bv = *(const float4*)&bias[c0];
        float cs0 = 0, cs1 = 0, cs2 = 0, cs3 = 0, cq0 = 0, cq1 = 0, cq2 = 0, cq3 = 0;
        #pragma unroll
        for (int j = 0; j < 4; ++j) {
            int r = row0 + r0 + j;
            if (r < NNODES) {
                float z0 = acc[j][0] + bv.x, z1 = acc[j][1] + bv.y;
                float z2 = acc[j][2] + bv.z, z3 = acc[j][3] + bv.w;
                *(uint2*)&Zb[(size_t)r * 50 + (c0 >> 1)] =
                    make_uint2(pack_bf16(z0, z1), pack_bf16(z2, z3));
                cs0 += z0; cs1 += z1; cs2 += z2; cs3 += z3;
                cq0 += z0 * z0; cq1 += z1 * z1; cq2 += z2 * z2; cq3 += z3 * z3;
            }
        }
        atomicAdd(&sSum[c0], cs0); atomicAdd(&sSum[c0 + 1], cs1);
        atomicAdd(&sSum[c0 + 2], cs2); atomicAdd(&sSum[c0 + 3], cs3);
        atomicAdd(&sSq[c0], cq0); atomicAdd(&sSq[c0 + 1], cq1);
        atomicAdd(&sSq[c0 + 2], cq2); atomicAdd(&sSq[c0 + 3], cq3);
    }
    __syncthreads();
    int sh = (blockIdx.x & (NSHARD - 1)) * SHSTRIDE;
    if (tid < CH) { atomicAdd(&gsum[sh + tid], sSum[tid]); atomicAdd(&gsq[sh + tid], sSq[tid]); }
}

// ---------------- layer-0 GEMM (512 thr, 4x4 tile, K=36, unroll-capped) ----------------
// Same shape as k_gemm_ch but K=36 and fp32 A input. #pragma unroll 1 on the
// k-loop prevents the full-unroll VGPR explosion (R13: 128 VGPR; R18 2-pass: 172).
// LDS = 14.4 + 9.2 + 0.8 = 24.4 KB -> 6 blocks/CU, plenty of waves to hide the
// serialized ds_reads.
__global__ __launch_bounds__(512) void k_gemm0(
    const float* __restrict__ A, const float* __restrict__ W, const float* __restrict__ bias,
    unsigned* __restrict__ Zb, float* __restrict__ gsum, float* __restrict__ gsq) {
    constexpr int K = CIN0, KP = 36;
    __shared__ __align__(16) float wS[KP * CH];   // 14.4 KB
    __shared__ __align__(16) float aS[64 * KP];   // 9.2 KB
    __shared__ float sSum[CH], sSq[CH];
    int tid = threadIdx.x;
    for (int i = tid; i < CH; i += 512) { sSum[i] = 0.f; sSq[i] = 0.f; }
    for (int i = tid; i < KP * CH; i += 512) wS[i] = (i < K * CH) ? W[i] : 0.f;
    int row0 = blockIdx.x * 64;
    {
        const float* As = A + (size_t)row0 * KP;
        int maxI = (NNODES - row0) * KP;
        for (int i = tid; i < 64 * KP; i += 512) aS[i] = (i < maxI) ? As[i] : 0.f;
    }
    __syncthreads();
    if (tid < 400) {
        int ct = tid % 25, rt = tid / 25;  // ct 0..24, rt 0..15
        int c0 = ct * 4, r0 = rt * 4;
        float acc[4][4] = {};
        #pragma unroll 1
        for (int k = 0; k < KP; k += 4) {
            float4 w0 = *(const float4*)&wS[(k + 0) * CH + c0];
            float4 w1 = *(const float4*)&wS[(k + 1) * CH + c0];
            float4 w2 = *(const float4*)&wS[(k + 2) * CH + c0];
            float4 w3 = *(const float4*)&wS[(k + 3) * CH + c0];
            #pragma unroll
            for (int j = 0; j < 4; ++j) {
                float4 av = *(const float4*)&aS[(r0 + j) * KP + k];
                acc[j][0] += av.x * w0.x + av.y * w1.x + av.z * w2.x + av.w * w3.x;
                acc[j][1] += av.x * w0.y + av.y * w1.y + av.z * w2.y + av.w * w3.y;
                acc[j][2] += av.x * w0.z + av.y * w1.z + av.z * w2.z + av.w * w3.z;
                acc[j][3] += av.x * w0.w + av.y * w1.w + av.z * w2.w + av.w * w3.w;
            }
        }
        float4 bv = *(const float4*)&bias[c0];
        float cs0 = 0, cs1 = 0, cs2 = 0, cs3 = 0, cq0 = 0, cq1 = 0, cq2 = 0, cq3 = 0;
        #pragma unroll
        for (int j = 0; j < 4; ++j) {
            int r = row0 + r0 + j;
            if (r < NNODES) {
                float z0 = acc[j][0] + bv.x, z1 = acc[j][1] + bv.y;
                float z2 = acc[j][2] + bv.z, z3 = acc[j][3] + bv.w;
                *(uint2*)&Zb[(size_t)r * 50 + (c0 >> 1)] =
                    make_uint2(pack_bf16(z0, z1), pack_bf16(z2, z3));
                cs0 += z0; cs1 += z1; cs2 += z2; cs3 += z3;
                cq0 += z0 * z0; cq1 += z1 * z1; cq2 += z2 * z2; cq3 += z3 * z3;
            }
        }
        atomicAdd(&sSum[c0], cs0); atomicAdd(&sSum[c0 + 1], cs1);
        atomicAdd(&sSum[c0 + 2], cs2); atomicAdd(&sSum[c0 + 3], cs3);
        atomicAdd(&sSq[c0], cq0); atomicAdd(&sSq[c0 + 1], cq1);
        atomicAdd(&sSq[c0 + 2], cq2); atomicAdd(&sSq[c0 + 3], cq3);
    }
    __syncthreads();
    int sh = (blockIdx.x & (NSHARD - 1)) * SHSTRIDE;
    if (tid < CH) { atomicAdd(&gsum[sh + tid], sSum[tid]); atomicAdd(&gsq[sh + tid], sSq[tid]); }
}

// ---------------- global_add_pool of BN(z) from bf16 Z; 4 row-chunks per graph ----------------
__global__ void k_pool(const unsigned* __restrict__ Zl, const int* __restrict__ batch,
                       const float* __restrict__ gsum, const float* __restrict__ gsq,
                       const float* __restrict__ gamma, const float* __restrict__ beta,
                       float* __restrict__ g) {
    int gid = blockIdx.x;
    int part = blockIdx.y;
    int lo = 0, hi = NNODES;
    while (lo < hi) { int mid = (lo + hi) >> 1; if (batch[mid] < gid) lo = mid + 1; else hi = mid; }
    int start = lo;
    hi = NNODES;
    while (lo < hi) { int mid = (lo + hi) >> 1; if (batch[mid] < gid + 1) lo = mid + 1; else hi = mid; }
    int end = lo;
    int len = end - start;
    int cb = (len + 3) >> 2;
    int s = start + part * cb;
    int e = s + cb; if (e > end) e = end;
    if (s >= e) return;
    int t = threadIdx.x;
    if (t >= 50) return;
    float su = 0.f, sv = 0.f, qu = 0.f, qv = 0.f;
    #pragma unroll
    for (int sh = 0; sh < NSHARD; ++sh) {
        float2 s2 = ((const float2*)(gsum + sh * SHSTRIDE))[t];
        float2 q2 = ((const float2*)(gsq + sh * SHSTRIDE))[t];
        su += s2.x; sv += s2.y; qu += q2.x; qv += q2.y;
    }
    constexpr float invN = 1.f / NNODES;
    float2 g2 = ((const float2*)gamma)[t];
    float2 b2 = ((const float2*)beta)[t];
    float mx = su * invN, my = sv * invN;
    float vx = qu * invN - mx * mx, vy = qv * invN - my * my;
    float scx = g2.x * rsqrtf(vx + BN_EPS), shx = b2.x - mx * scx;
    float scy = g2.y * rsqrtf(vy + BN_EPS), shy = b2.y - my * scy;
    float sx = 0.f, sy = 0.f;
    for (int r = s; r < e; ++r) {
        unsigned v = Zl[(size_t)r * 50 + t];
        sx += unp_lo(v); sy += unp_hi(v);
    }
    float n = (float)(e - s);
    atomicAdd(&g[gid * CH + 2 * t], sx * scx + n * shx);
    atomicAdd(&g[gid * CH + 2 * t + 1], sy * scy + n * shy);
}

// ---------------- out = leakyrelu(g @ Wout + bout, 0.1) ----------------
__global__ __launch_bounds__(256) void k_out(const float* __restrict__ g,
                                             const float* __restrict__ Wout,
                                             const float* __restrict__ bout,
                                             float* __restrict__ out) {
    __shared__ float gS[CH];
    int gid = blockIdx.x, tid = threadIdx.x;
    if (tid < CH) gS[tid] = g[gid * CH + tid];
    __syncthreads();
    if (tid >= 200) return;
    float acc = bout[tid];
    for (int k = 0; k < CH; ++k) acc += gS[k] * Wout[k * 200 + tid];
    out[gid * 200 + tid] = acc > 0.f ? acc : 0.1f * acc;
}

extern "C" void kernel_launch(void* const* d_in, const int* in_sizes, int n_in,
                              void* d_out, int out_size, void* d_ws, size_t ws_size,
                              hipStream_t stream) {
    const float* x = (const float*)d_in[0];
    const int* ei = (const int*)d_in[1];
    const int* batch = (const int*)d_in[2];
    const float* W0 = (const float*)d_in[3];
    const float* Wrest = (const float*)d_in[4];
    const float* b = (const float*)d_in[5];
    const float* gamma = (const float*)d_in[6];
    const float* beta = (const float*)d_in[7];
    const float* Wout = (const float*)d_in[8];
    const float* bout = (const float*)d_in[9];
    float* out = (float*)d_out;
    const int* srcA = ei;
    const int* dstA = ei + NEDGES;

    char* wsb = (char*)d_ws;
    size_t off = 0;
    auto alloc = [&](size_t elems) -> void* {
        void* p = (void*)(wsb + off);
        off += ((elems + 7) & ~(size_t)7) * 4;
        return p;
    };
    int* cnt = (int*)alloc(NNODES);
    int* rowptr = (int*)alloc(NNODES + 1);
    int* cursor = (int*)alloc(NNODES);
    float* dinv = (float*)alloc(NNODES);
    int* scanBlk = (int*)alloc(64);
    int* scanOff = (int*)alloc(64);
    float* stats = (float*)alloc(NSHARD * SHSTRIDE);  // per shard: [l*128]=sum, [512+l*128]=sq
    int2* ew = (int2*)alloc(2 * (size_t)NEDGES);
    unsigned* xb = (unsigned*)alloc((size_t)NNODES * 17);
    float* A0 = (float*)alloc((size_t)NNODES * 36);
    unsigned* Abf = (unsigned*)alloc((size_t)NNODES * 50);
    unsigned* Zb = (unsigned*)alloc((size_t)NNODES * 50);
    float* gbuf = (float*)alloc((size_t)NGRAPH * CH);
    (void)ws_size; (void)n_in; (void)in_sizes; (void)out_size;

    hipLaunchKernelGGL(k_init, dim3((NNODES + 255) / 256), dim3(256), 0, stream, cnt, stats, gbuf);
    hipLaunchKernelGGL(k_hist, dim3((NEDGES + 255) / 256), dim3(256), 0, stream, dstA, cnt);
    hipLaunchKernelGGL(k_packx, dim3((NNODES * 17 + 255) / 256), dim3(256), 0, stream, x, xb);
    hipLaunchKernelGGL(k_scan1, dim3(SCAN_BLOCKS), dim3(SCAN_TPB), 0, stream, cnt, rowptr, scanBlk, dinv);
    hipLaunchKernelGGL(k_scan2, dim3(1), dim3(64), 0, stream, scanBlk, scanOff);
    hipLaunchKernelGGL(k_scan3, dim3(SCAN_BLOCKS), dim3(SCAN_TPB), 0, stream, rowptr, cursor, scanOff);
    hipLaunchKernelGGL(k_scatter, dim3((NEDGES + 255) / 256), dim3(256), 0, stream,
                       srcA, dstA, dinv, cursor, ew);

    for (int l = 0; l < 4; ++l) {
        float* gs = stats + l * 128;          // + shard*SHSTRIDE inside kernels
        float* gq = stats + 512 + l * 128;
        if (l == 0) {
            hipLaunchKernelGGL((k_aggregate_bf16<17, 36, false, false>), dim3(12500), dim3(256), 0,
                               stream, xb, A0, rowptr, ew, dinv,
                               (const float*)nullptr, (const float*)nullptr,
                               (const float*)nullptr, (const float*)nullptr);
            hipLaunchKernelGGL(k_gemm0, dim3((NNODES + 63) / 64), dim3(512), 0, stream,
                               A0, W0, b, Zb, gs, gq);
        } else {
            float* ps = stats + (l - 1) * 128;
            float* pq = stats + 512 + (l - 1) * 128;
            hipLaunchKernelGGL((k_aggregate_bf16<50, 50, true, true>), dim3(12500), dim3(256), 0,
                               stream, Zb, Abf, rowptr, ew, dinv,
                               ps, pq, gamma + (l - 1) * CH, beta + (l - 1) * CH);
            hipLaunchKernelGGL(k_gemm_ch, dim3((NNODES + 63) / 64), dim3(512), 0, stream,
                               Abf, Wrest + (l - 1) * 10000, b + l * CH, Zb, gs, gq);
        }
    }
    hipLaunchKernelGGL(k_pool, dim3(NGRAPH, 4), dim3(64), 0, stream, Zb, batch,
                       stats + 3 * 128, stats + 512 + 3 * 128, gamma + 3 * CH, beta + 3 * CH, gbuf);
    hipLaunchKernelGGL(k_out, dim3(NGRAPH), dim3(256), 0, stream, gbuf, Wout, bout, out);
}